// Round 1
// baseline (11883.478 us; speedup 1.0000x reference)
//
#include <hip/hip_runtime.h>
#include <stdint.h>

#define D 128
constexpr int NUc = 50000, NSc = 10000, NVc = 30000, Bc = 2048;

// ---------------- Threefry-2x32 (JAX) ----------------
__host__ __device__ inline void threefry(uint32_t k0, uint32_t k1, uint32_t x0, uint32_t x1,
                                         uint32_t& o0, uint32_t& o1) {
  uint32_t ks2 = k0 ^ k1 ^ 0x1BD11BDAu;
  uint32_t v0 = x0 + k0, v1 = x1 + k1;
#define TFR(r) { v0 += v1; v1 = (v1 << (r)) | (v1 >> (32 - (r))); v1 ^= v0; }
  TFR(13) TFR(15) TFR(26) TFR(6)   v0 += k1;  v1 += ks2 + 1u;
  TFR(17) TFR(29) TFR(16) TFR(24)  v0 += ks2; v1 += k0 + 2u;
  TFR(13) TFR(15) TFR(26) TFR(6)   v0 += k0;  v1 += k1 + 3u;
  TFR(17) TFR(29) TFR(16) TFR(24)  v0 += k1;  v1 += ks2 + 4u;
  TFR(13) TFR(15) TFR(26) TFR(6)   v0 += ks2; v1 += k0 + 5u;
#undef TFR
  o0 = v0; o1 = v1;
}

// partitionable-mode uniform [0,1): bits = h0(0,j) ^ h1(0,j)
__device__ __forceinline__ float unif01(uint32_t k0, uint32_t k1, uint32_t j) {
  uint32_t a, b;
  threefry(k0, k1, 0u, j, a, b);
  uint32_t bits = a ^ b;
  return __uint_as_float(0x3F800000u | (bits >> 9)) - 1.0f;
}

// ---------------- kernels ----------------
__global__ void k_concat(const float* __restrict__ a, int na, const float* __restrict__ b, int nb,
                         float* __restrict__ feats, float* __restrict__ acc) {
  size_t idx = (size_t)blockIdx.x * blockDim.x + threadIdx.x;  // float4 units
  size_t tot = (size_t)(na + nb) * (D / 4);
  if (idx >= tot) return;
  size_t aEnd = (size_t)na * (D / 4);
  float4 v = (idx < aEnd) ? ((const float4*)a)[idx] : ((const float4*)b)[idx - aEnd];
  ((float4*)feats)[idx] = v;
  ((float4*)acc)[idx] = v;
}

__global__ void k_spmm(const int* __restrict__ rows, const int* __restrict__ cols,
                       const float* __restrict__ vals, const float* __restrict__ x,
                       float* __restrict__ out, int nnz) {
  size_t idx = (size_t)blockIdx.x * blockDim.x + threadIdx.x;
  int e = (int)(idx >> 5);
  int l = (int)(idx & 31);
  if (e >= nnz) return;
  int r = rows[e], c = cols[e];
  float v = vals[e];
  float4 xv = ((const float4*)(x + (size_t)c * D))[l];
  float* o = out + (size_t)r * D + (size_t)l * 4;
  atomicAdd(o + 0, v * xv.x);
  atomicAdd(o + 1, v * xv.y);
  atomicAdd(o + 2, v * xv.z);
  atomicAdd(o + 3, v * xv.w);
}

// feats_new = tmp + sign(tmp)*l2(noise)*eps ; acc = (acc + l2(feats_new)) / div ; feats = feats_new
__global__ void k_prop_noise(const float* __restrict__ tmp, float* __restrict__ feats,
                             float* __restrict__ acc, int nrows, float eps, float div,
                             unsigned k0, unsigned k1) {
  int gid = blockIdx.x * blockDim.x + threadIdx.x;
  int wave = gid >> 6, lane = gid & 63;
  if (wave >= nrows) return;
  size_t base = (size_t)wave * D + lane * 2;
  float2 f = *(const float2*)(tmp + base);
  uint32_t j0 = (uint32_t)base;
  float u0 = unif01(k0, k1, j0);
  float u1 = unif01(k0, k1, j0 + 1u);
  float s2 = u0 * u0 + u1 * u1;
  for (int m = 1; m < 64; m <<= 1) s2 += __shfl_xor(s2, m, 64);
  float nn = fmaxf(sqrtf(s2), 1e-12f);
  float sg0 = (f.x > 0.f) ? 1.f : ((f.x < 0.f) ? -1.f : 0.f);
  float sg1 = (f.y > 0.f) ? 1.f : ((f.y < 0.f) ? -1.f : 0.f);
  float nf0 = f.x + sg0 * (u0 / nn) * eps;
  float nf1 = f.y + sg1 * (u1 / nn) * eps;
  float fs = nf0 * nf0 + nf1 * nf1;
  for (int m = 1; m < 64; m <<= 1) fs += __shfl_xor(fs, m, 64);
  float fn = fmaxf(sqrtf(fs), 1e-12f);
  float2 a = *(const float2*)(acc + base);
  a.x = (a.x + nf0 / fn) / div;
  a.y = (a.y + nf1 / fn) / div;
  *(float2*)(acc + base) = a;
  *(float2*)(feats + base) = float2{nf0, nf1};
}

// out = tmp + sign(tmp)*l2(noise)*eps
__global__ void k_agg_noise(const float* __restrict__ tmp, float* __restrict__ out,
                            int nrows, float eps, unsigned k0, unsigned k1) {
  int gid = blockIdx.x * blockDim.x + threadIdx.x;
  int wave = gid >> 6, lane = gid & 63;
  if (wave >= nrows) return;
  size_t base = (size_t)wave * D + lane * 2;
  float2 f = *(const float2*)(tmp + base);
  uint32_t j0 = (uint32_t)base;
  float u0 = unif01(k0, k1, j0);
  float u1 = unif01(k0, k1, j0 + 1u);
  float s2 = u0 * u0 + u1 * u1;
  for (int m = 1; m < 64; m <<= 1) s2 += __shfl_xor(s2, m, 64);
  float nn = fmaxf(sqrtf(s2), 1e-12f);
  float sg0 = (f.x > 0.f) ? 1.f : ((f.x < 0.f) ? -1.f : 0.f);
  float sg1 = (f.y > 0.f) ? 1.f : ((f.y < 0.f) ? -1.f : 0.f);
  *(float2*)(out + base) = float2{f.x + sg0 * (u0 / nn) * eps, f.y + sg1 * (u1 / nn) * eps};
}

// attention over 3 embeddings, in-place into e0buf
__global__ void k_mga(float* __restrict__ e0buf, const float* __restrict__ UVm,
                      const float* __restrict__ UVs, const float* __restrict__ SVu,
                      const float* __restrict__ SVm, const float* __restrict__ w,
                      const float* __restrict__ bptr) {
  int gid = blockIdx.x * blockDim.x + threadIdx.x;
  int wave = gid >> 6, lane = gid & 63;
  int n = NUc + NSc;
  if (wave >= n) return;
  const float* e1 = (wave < NUc) ? (UVm + (size_t)wave * D) : (UVs + (size_t)(wave - NUc) * D);
  const float* e2 = (wave < NUc) ? (SVu + (size_t)wave * D) : (SVm + (size_t)(wave - NUc) * D);
  float* e0 = e0buf + (size_t)wave * D;
  int c = lane * 2;
  float2 v0 = *(const float2*)(e0 + c);
  float2 v1 = *(const float2*)(e1 + c);
  float2 v2 = *(const float2*)(e2 + c);
  float2 wl = *(const float2*)(w + c);
  float2 wh = *(const float2*)(w + D + c);
  float d00 = v0.x * wl.x + v0.y * wl.y;
  float c0 = v0.x * wh.x + v0.y * wh.y;
  float c1 = v1.x * wh.x + v1.y * wh.y;
  float c2 = v2.x * wh.x + v2.y * wh.y;
  for (int m = 1; m < 64; m <<= 1) {
    d00 += __shfl_xor(d00, m, 64);
    c0 += __shfl_xor(c0, m, 64);
    c1 += __shfl_xor(c1, m, 64);
    c2 += __shfl_xor(c2, m, 64);
  }
  float b = bptr[0];
  float l0 = d00 + c0 + b, l1 = d00 + c1 + b, l2v = d00 + c2 + b;
  float mx = fmaxf(l0, fmaxf(l1, l2v));
  float a0 = expf(l0 - mx), a1 = expf(l1 - mx), a2 = expf(l2v - mx);
  float s = a0 + a1 + a2;
  a0 /= s; a1 /= s; a2 /= s;
  float2 o;
  o.x = a0 * v0.x + a1 * v1.x + a2 * v2.x;
  o.y = a0 * v0.y + a1 * v1.y + a2 * v2.y;
  *(float2*)(e0 + c) = o;
}

// gather batch rows: BPR accumulation + normalized P rows
__global__ void k_batch(const float* __restrict__ reps, const int* __restrict__ users,
                        const int* __restrict__ streamers, float* __restrict__ Pu,
                        float* __restrict__ Ps, float* __restrict__ accs) {
  int gid = blockIdx.x * blockDim.x + threadIdx.x;
  int wave = gid >> 6, lane = gid & 63;
  if (wave >= Bc) return;
  int u = users[wave];
  int s0 = streamers[wave * 2], s1 = streamers[wave * 2 + 1];
  const float2* ur = (const float2*)(reps + (size_t)u * D);
  const float2* ar = (const float2*)(reps + (size_t)(NUc + s0) * D);
  const float2* cr = (const float2*)(reps + (size_t)(NUc + s1) * D);
  float2 uv = ur[lane], av = ar[lane], cv = cr[lane];
  float p0 = uv.x * av.x + uv.y * av.y;
  float p1 = uv.x * cv.x + uv.y * cv.y;
  float un = uv.x * uv.x + uv.y * uv.y;
  float an = av.x * av.x + av.y * av.y;
  for (int m = 1; m < 64; m <<= 1) {
    p0 += __shfl_xor(p0, m, 64);
    p1 += __shfl_xor(p1, m, 64);
    un += __shfl_xor(un, m, 64);
    an += __shfl_xor(an, m, 64);
  }
  if (lane == 0) {
    float t = p0 - p1;
    float term = fmaxf(-t, 0.f) + log1pf(expf(-fabsf(t)));  // -log_sigmoid(t)
    atomicAdd(&accs[0], term);
  }
  float und = fmaxf(sqrtf(un), 1e-12f);
  float andv = fmaxf(sqrtf(an), 1e-12f);
  ((float2*)(Pu + (size_t)wave * D))[lane] = float2{uv.x / und, uv.y / und};
  ((float2*)(Ps + (size_t)wave * D))[lane] = float2{av.x / andv, av.y / andv};
}

// per-row: ttl = logsumexp_j(dot(p_b,p_j)/0.2); acc += ttl - pos
__global__ __launch_bounds__(256) void k_closs(const float* __restrict__ P, float* __restrict__ acc) {
  __shared__ float prow[D];
  __shared__ float sm[4], ss[4];
  int b = blockIdx.x;
  int tid = threadIdx.x;
  if (tid < D) prow[tid] = P[(size_t)b * D + tid];
  __syncthreads();
  float m = -3.4e38f, s = 0.f;
  for (int j = tid; j < Bc; j += 256) {
    const float4* pj = (const float4*)(P + (size_t)j * D);
    const float4* pr = (const float4*)prow;
    float d = 0.f;
#pragma unroll
    for (int t = 0; t < D / 4; ++t) {
      float4 q = pj[t], p = pr[t];
      d = fmaf(p.x, q.x, d); d = fmaf(p.y, q.y, d);
      d = fmaf(p.z, q.z, d); d = fmaf(p.w, q.w, d);
    }
    d *= 5.0f;  // /C_TEMP
    if (d > m) { s = s * expf(m - d) + 1.0f; m = d; }
    else s += expf(d - m);
  }
  for (int o = 1; o < 64; o <<= 1) {
    float om = __shfl_xor(m, o, 64), os = __shfl_xor(s, o, 64);
    float M = fmaxf(m, om);
    s = s * expf(m - M) + os * expf(om - M);
    m = M;
  }
  int w = tid >> 6;
  if ((tid & 63) == 0) { sm[w] = m; ss[w] = s; }
  __syncthreads();
  if (tid == 0) {
    float M = fmaxf(fmaxf(sm[0], sm[1]), fmaxf(sm[2], sm[3]));
    float S = ss[0] * expf(sm[0] - M) + ss[1] * expf(sm[1] - M) +
              ss[2] * expf(sm[2] - M) + ss[3] * expf(sm[3] - M);
    float ttl = M + logf(S);
    float pos = 0.f;
    for (int t = 0; t < D; ++t) pos = fmaf(prow[t], prow[t], pos);
    pos *= 5.0f;
    atomicAdd(acc, ttl - pos);
  }
}

__global__ void k_final(const float* __restrict__ accs, float* __restrict__ out) {
  if (threadIdx.x == 0 && blockIdx.x == 0) {
    out[0] = accs[0] / (float)Bc;
    out[1] = 0.5f * (accs[1] + accs[2]) / (float)Bc;
  }
}

// ---------------- launch ----------------
extern "C" void kernel_launch(void* const* d_in, const int* in_sizes, int n_in,
                              void* d_out, int out_size, void* d_ws, size_t ws_size,
                              hipStream_t stream) {
  const float* usersF = (const float*)d_in[0];
  const float* streamersF = (const float*)d_in[1];
  const float* videosF = (const float*)d_in[2];
  const float* linW = (const float*)d_in[3];
  const float* linB = (const float*)d_in[4];
  const int* us_row = (const int*)d_in[5];
  const int* us_col = (const int*)d_in[6];
  const float* us_val = (const float*)d_in[7];
  const int* uv_row = (const int*)d_in[8];
  const int* uv_col = (const int*)d_in[9];
  const float* uv_val = (const float*)d_in[10];
  const int* sv_row = (const int*)d_in[11];
  const int* sv_col = (const int*)d_in[12];
  const float* sv_val = (const float*)d_in[13];
  const int* uva_row = (const int*)d_in[14];
  const int* uva_col = (const int*)d_in[15];
  const float* uva_val = (const float*)d_in[16];
  const int* sva_row = (const int*)d_in[17];
  const int* sva_col = (const int*)d_in[18];
  const float* sva_val = (const float*)d_in[19];
  const int* users = (const int*)d_in[20];
  const int* streamers = (const int*)d_in[21];
  const int nnz_us = in_sizes[5], nnz_uv = in_sizes[8], nnz_sv = in_sizes[11];
  const int nnz_uva = in_sizes[14], nnz_sva = in_sizes[17];
  float* out = (float*)d_out;

  float* ws = (float*)d_ws;
  size_t o = 0;
  float* UVm = ws + o; o += (size_t)(NUc + NVc) * D;
  float* SVm = ws + o; o += (size_t)(NSc + NVc) * D;
  float* USm = ws + o; o += (size_t)(NUc + NSc) * D;
  float* UVs = ws + o; o += (size_t)NSc * D;
  float* SVu = ws + o; o += (size_t)NUc * D;
  float* F   = ws + o; o += (size_t)(NUc + NVc) * D;
  float* T   = ws + o; o += (size_t)(NUc + NVc) * D;
  // alias into F (dead after US propagation)
  float* Pu = F;
  float* Ps = F + (size_t)Bc * D;
  float* accs = F + (size_t)2 * Bc * D;

  // key derivation (JAX threefry, partitionable/fold-like split)
  uint32_t kus[2], kuv[2], ksv[2], kauv[2], kasv[2];
  threefry(0u, 42u, 0u, 0u, kus[0], kus[1]);
  threefry(0u, 42u, 0u, 1u, kuv[0], kuv[1]);
  threefry(0u, 42u, 0u, 2u, ksv[0], ksv[1]);
  threefry(0u, 42u, 0u, 3u, kauv[0], kauv[1]);
  threefry(0u, 42u, 0u, 4u, kasv[0], kasv[1]);
  uint32_t kusL[2][2], kuvL[2][2], ksvL[2][2];
  for (uint32_t i = 0; i < 2; ++i) {
    threefry(kus[0], kus[1], 0u, i, kusL[i][0], kusL[i][1]);
    threefry(kuv[0], kuv[1], 0u, i, kuvL[i][0], kuvL[i][1]);
    threefry(ksv[0], ksv[1], 0u, i, ksvL[i][0], ksvL[i][1]);
  }

  auto run_prop = [&](const float* a, int na, const float* b, int nb, const int* grow,
                      const int* gcol, const float* gval, int nnz, float* acc,
                      const uint32_t (&kL)[2][2]) {
    int n = na + nb;
    size_t tot4 = (size_t)n * (D / 4);
    k_concat<<<(unsigned)((tot4 + 255) / 256), 256, 0, stream>>>(a, na, b, nb, F, acc);
    for (int i = 0; i < 2; ++i) {
      hipMemsetAsync(T, 0, (size_t)n * D * sizeof(float), stream);
      size_t th = (size_t)nnz * 32;
      k_spmm<<<(unsigned)((th + 255) / 256), 256, 0, stream>>>(grow, gcol, gval, F, T, nnz);
      float div = (i == 1) ? 3.0f : 1.0f;
      k_prop_noise<<<(unsigned)((n + 3) / 4), 256, 0, stream>>>(T, F, acc, n, 0.1f, div,
                                                                kL[i][0], kL[i][1]);
    }
  };
  auto run_agg = [&](const int* grow, const int* gcol, const float* gval, int nnz,
                     const float* x, int n_out, float* dst, const uint32_t (&k)[2]) {
    hipMemsetAsync(T, 0, (size_t)n_out * D * sizeof(float), stream);
    size_t th = (size_t)nnz * 32;
    k_spmm<<<(unsigned)((th + 255) / 256), 256, 0, stream>>>(grow, gcol, gval, x, T, nnz);
    k_agg_noise<<<(unsigned)((n_out + 3) / 4), 256, 0, stream>>>(T, dst, n_out, 0.1f, k[0], k[1]);
  };

  // UV propagate -> UVm ; UV_s aggregate (video part of UVm)
  run_prop(usersF, NUc, videosF, NVc, uv_row, uv_col, uv_val, nnz_uv, UVm, kuvL);
  run_agg(sva_row, sva_col, sva_val, nnz_sva, UVm + (size_t)NUc * D, NSc, UVs, kasv);
  // SV propagate -> SVm ; SV_u aggregate (video part of SVm)
  run_prop(streamersF, NSc, videosF, NVc, sv_row, sv_col, sv_val, nnz_sv, SVm, ksvL);
  run_agg(uva_row, uva_col, uva_val, nnz_uva, SVm + (size_t)NSc * D, NUc, SVu, kauv);
  // US propagate -> USm
  run_prop(usersF, NUc, streamersF, NSc, us_row, us_col, us_val, nnz_us, USm, kusL);
  // MGA attention in-place into USm -> [users_rep ; streamers_rep]
  k_mga<<<(unsigned)((NUc + NSc + 3) / 4), 256, 0, stream>>>(USm, UVm, UVs, SVu, SVm, linW, linB);
  // losses
  hipMemsetAsync(accs, 0, 16 * sizeof(float), stream);
  k_batch<<<(unsigned)((Bc + 3) / 4), 256, 0, stream>>>(USm, users, streamers, Pu, Ps, accs);
  k_closs<<<Bc, 256, 0, stream>>>(Pu, accs + 1);
  k_closs<<<Bc, 256, 0, stream>>>(Ps, accs + 2);
  k_final<<<1, 64, 0, stream>>>(accs, out);
}

// Round 2
// 2052.568 us; speedup vs baseline: 5.7896x; 5.7896x over previous
//
#include <hip/hip_runtime.h>
#include <stdint.h>

#define D 128
constexpr int NUc = 50000, NSc = 10000, NVc = 30000, Bc = 2048;

// ---------------- Threefry-2x32 (JAX) ----------------
__host__ __device__ inline void threefry(uint32_t k0, uint32_t k1, uint32_t x0, uint32_t x1,
                                         uint32_t& o0, uint32_t& o1) {
  uint32_t ks2 = k0 ^ k1 ^ 0x1BD11BDAu;
  uint32_t v0 = x0 + k0, v1 = x1 + k1;
#define TFR(r) { v0 += v1; v1 = (v1 << (r)) | (v1 >> (32 - (r))); v1 ^= v0; }
  TFR(13) TFR(15) TFR(26) TFR(6)   v0 += k1;  v1 += ks2 + 1u;
  TFR(17) TFR(29) TFR(16) TFR(24)  v0 += ks2; v1 += k0 + 2u;
  TFR(13) TFR(15) TFR(26) TFR(6)   v0 += k0;  v1 += k1 + 3u;
  TFR(17) TFR(29) TFR(16) TFR(24)  v0 += k1;  v1 += ks2 + 4u;
  TFR(13) TFR(15) TFR(26) TFR(6)   v0 += ks2; v1 += k0 + 5u;
#undef TFR
  o0 = v0; o1 = v1;
}

__device__ __forceinline__ float unif01(uint32_t k0, uint32_t k1, uint32_t j) {
  uint32_t a, b;
  threefry(k0, k1, 0u, j, a, b);
  uint32_t bits = a ^ b;
  return __uint_as_float(0x3F800000u | (bits >> 9)) - 1.0f;
}

// ---------------- CSR build ----------------
__global__ void k_hist(const int* __restrict__ rows, int nnz, int* __restrict__ counts) {
  int e = blockIdx.x * blockDim.x + threadIdx.x;
  if (e < nnz) atomicAdd(&counts[rows[e] + 1], 1);
}

// single-block inclusive scan (n up to ~80001)
__global__ __launch_bounds__(1024) void k_scan(int* __restrict__ data, int n) {
  __shared__ int wsum[16];
  __shared__ int carry_s;
  int tid = threadIdx.x, lane = tid & 63, w = tid >> 6;
  if (tid == 0) carry_s = 0;
  __syncthreads();
  for (int base = 0; base < n; base += 1024) {
    int i = base + tid;
    int v = (i < n) ? data[i] : 0;
    int x = v;
    for (int off = 1; off < 64; off <<= 1) {
      int t = __shfl_up(x, off, 64);
      if (lane >= off) x += t;
    }
    if (lane == 63) wsum[w] = x;
    __syncthreads();                       // A
    if (w == 0 && lane < 16) {
      int s = wsum[lane];
      for (int off = 1; off < 16; off <<= 1) {
        int t = __shfl_up(s, off, 64);
        if (lane >= off) s += t;
      }
      wsum[lane] = s;
    }
    __syncthreads();                       // B
    int woff = (w > 0) ? wsum[w - 1] : 0;
    int out = x + woff + carry_s;
    if (i < n) data[i] = out;
    int total = wsum[15];
    __syncthreads();                       // C
    if (tid == 0) carry_s += total;
  }
}

__global__ void k_copy(const int* __restrict__ src, int* __restrict__ dst, int n) {
  int i = blockIdx.x * blockDim.x + threadIdx.x;
  if (i < n) dst[i] = src[i];
}

__global__ void k_scatter(const int* __restrict__ rows, const int* __restrict__ cols,
                          const float* __restrict__ vals, int nnz, int* __restrict__ cursor,
                          int2* __restrict__ cv) {
  int e = blockIdx.x * blockDim.x + threadIdx.x;
  if (e >= nnz) return;
  int pos = atomicAdd(&cursor[rows[e]], 1);
  cv[pos] = make_int2(cols[e], __float_as_int(vals[e]));
}

// ---------------- feature kernels ----------------
__global__ void k_concat(const float* __restrict__ a, int na, const float* __restrict__ b, int nb,
                         float* __restrict__ feats, float* __restrict__ acc) {
  size_t idx = (size_t)blockIdx.x * blockDim.x + threadIdx.x;  // float4 units
  size_t tot = (size_t)(na + nb) * (D / 4);
  if (idx >= tot) return;
  size_t aEnd = (size_t)na * (D / 4);
  float4 v = (idx < aEnd) ? ((const float4*)a)[idx] : ((const float4*)b)[idx - aEnd];
  ((float4*)feats)[idx] = v;
  ((float4*)acc)[idx] = v;
}

// gather SpMM (wave per row) + fused propagate-noise epilogue
__global__ void k_gprop(const int* __restrict__ rp, const int2* __restrict__ cv,
                        const float* __restrict__ src, float* __restrict__ dst,
                        float* __restrict__ acc, int nrows, float eps, float div,
                        unsigned k0, unsigned k1) {
  int gid = blockIdx.x * blockDim.x + threadIdx.x;
  int r = gid >> 6, lane = gid & 63;
  if (r >= nrows) return;
  int s = rp[r], e = rp[r + 1];
  const float2* sp = (const float2*)src;
  float fx = 0.f, fy = 0.f;
  for (int k = s; k < e; ++k) {
    int2 p = cv[k];
    float v = __int_as_float(p.y);
    float2 xv = sp[(size_t)p.x * (D / 2) + lane];
    fx = fmaf(v, xv.x, fx);
    fy = fmaf(v, xv.y, fy);
  }
  size_t base = (size_t)r * D + lane * 2;
  uint32_t j0 = (uint32_t)base;
  float u0 = unif01(k0, k1, j0);
  float u1 = unif01(k0, k1, j0 + 1u);
  float s2 = u0 * u0 + u1 * u1;
  for (int m = 1; m < 64; m <<= 1) s2 += __shfl_xor(s2, m, 64);
  float nn = fmaxf(sqrtf(s2), 1e-12f);
  float sg0 = (fx > 0.f) ? 1.f : ((fx < 0.f) ? -1.f : 0.f);
  float sg1 = (fy > 0.f) ? 1.f : ((fy < 0.f) ? -1.f : 0.f);
  float nf0 = fx + sg0 * (u0 / nn) * eps;
  float nf1 = fy + sg1 * (u1 / nn) * eps;
  float fs = nf0 * nf0 + nf1 * nf1;
  for (int m = 1; m < 64; m <<= 1) fs += __shfl_xor(fs, m, 64);
  float fn = fmaxf(sqrtf(fs), 1e-12f);
  float2 a = *(const float2*)(acc + base);
  a.x = (a.x + nf0 / fn) / div;
  a.y = (a.y + nf1 / fn) / div;
  *(float2*)(acc + base) = a;
  *(float2*)(dst + base) = float2{nf0, nf1};
}

// gather SpMM (wave per row) + fused aggregate-noise epilogue
__global__ void k_gagg(const int* __restrict__ rp, const int2* __restrict__ cv,
                       const float* __restrict__ src, float* __restrict__ dst,
                       int nrows, float eps, unsigned k0, unsigned k1) {
  int gid = blockIdx.x * blockDim.x + threadIdx.x;
  int r = gid >> 6, lane = gid & 63;
  if (r >= nrows) return;
  int s = rp[r], e = rp[r + 1];
  const float2* sp = (const float2*)src;
  float fx = 0.f, fy = 0.f;
  for (int k = s; k < e; ++k) {
    int2 p = cv[k];
    float v = __int_as_float(p.y);
    float2 xv = sp[(size_t)p.x * (D / 2) + lane];
    fx = fmaf(v, xv.x, fx);
    fy = fmaf(v, xv.y, fy);
  }
  size_t base = (size_t)r * D + lane * 2;
  uint32_t j0 = (uint32_t)base;
  float u0 = unif01(k0, k1, j0);
  float u1 = unif01(k0, k1, j0 + 1u);
  float s2 = u0 * u0 + u1 * u1;
  for (int m = 1; m < 64; m <<= 1) s2 += __shfl_xor(s2, m, 64);
  float nn = fmaxf(sqrtf(s2), 1e-12f);
  float sg0 = (fx > 0.f) ? 1.f : ((fx < 0.f) ? -1.f : 0.f);
  float sg1 = (fy > 0.f) ? 1.f : ((fy < 0.f) ? -1.f : 0.f);
  *(float2*)(dst + base) = float2{fx + sg0 * (u0 / nn) * eps, fy + sg1 * (u1 / nn) * eps};
}

// attention over 3 embeddings, in-place into e0buf
__global__ void k_mga(float* __restrict__ e0buf, const float* __restrict__ UVm,
                      const float* __restrict__ UVs, const float* __restrict__ SVu,
                      const float* __restrict__ SVm, const float* __restrict__ w,
                      const float* __restrict__ bptr) {
  int gid = blockIdx.x * blockDim.x + threadIdx.x;
  int wave = gid >> 6, lane = gid & 63;
  int n = NUc + NSc;
  if (wave >= n) return;
  const float* e1 = (wave < NUc) ? (UVm + (size_t)wave * D) : (UVs + (size_t)(wave - NUc) * D);
  const float* e2 = (wave < NUc) ? (SVu + (size_t)wave * D) : (SVm + (size_t)(wave - NUc) * D);
  float* e0 = e0buf + (size_t)wave * D;
  int c = lane * 2;
  float2 v0 = *(const float2*)(e0 + c);
  float2 v1 = *(const float2*)(e1 + c);
  float2 v2 = *(const float2*)(e2 + c);
  float2 wl = *(const float2*)(w + c);
  float2 wh = *(const float2*)(w + D + c);
  float d00 = v0.x * wl.x + v0.y * wl.y;
  float c0 = v0.x * wh.x + v0.y * wh.y;
  float c1 = v1.x * wh.x + v1.y * wh.y;
  float c2 = v2.x * wh.x + v2.y * wh.y;
  for (int m = 1; m < 64; m <<= 1) {
    d00 += __shfl_xor(d00, m, 64);
    c0 += __shfl_xor(c0, m, 64);
    c1 += __shfl_xor(c1, m, 64);
    c2 += __shfl_xor(c2, m, 64);
  }
  float b = bptr[0];
  float l0 = d00 + c0 + b, l1 = d00 + c1 + b, l2v = d00 + c2 + b;
  float mx = fmaxf(l0, fmaxf(l1, l2v));
  float a0 = expf(l0 - mx), a1 = expf(l1 - mx), a2 = expf(l2v - mx);
  float s = a0 + a1 + a2;
  a0 /= s; a1 /= s; a2 /= s;
  float2 o;
  o.x = a0 * v0.x + a1 * v1.x + a2 * v2.x;
  o.y = a0 * v0.y + a1 * v1.y + a2 * v2.y;
  *(float2*)(e0 + c) = o;
}

// gather batch rows: BPR accumulation + normalized P rows
__global__ void k_batch(const float* __restrict__ reps, const int* __restrict__ users,
                        const int* __restrict__ streamers, float* __restrict__ Pu,
                        float* __restrict__ Ps, float* __restrict__ accs) {
  int gid = blockIdx.x * blockDim.x + threadIdx.x;
  int wave = gid >> 6, lane = gid & 63;
  if (wave >= Bc) return;
  int u = users[wave];
  int s0 = streamers[wave * 2], s1 = streamers[wave * 2 + 1];
  const float2* ur = (const float2*)(reps + (size_t)u * D);
  const float2* ar = (const float2*)(reps + (size_t)(NUc + s0) * D);
  const float2* cr = (const float2*)(reps + (size_t)(NUc + s1) * D);
  float2 uv = ur[lane], av = ar[lane], cv = cr[lane];
  float p0 = uv.x * av.x + uv.y * av.y;
  float p1 = uv.x * cv.x + uv.y * cv.y;
  float un = uv.x * uv.x + uv.y * uv.y;
  float an = av.x * av.x + av.y * av.y;
  for (int m = 1; m < 64; m <<= 1) {
    p0 += __shfl_xor(p0, m, 64);
    p1 += __shfl_xor(p1, m, 64);
    un += __shfl_xor(un, m, 64);
    an += __shfl_xor(an, m, 64);
  }
  if (lane == 0) {
    float t = p0 - p1;
    float term = fmaxf(-t, 0.f) + log1pf(expf(-fabsf(t)));  // -log_sigmoid(t)
    atomicAdd(&accs[0], term);
  }
  float und = fmaxf(sqrtf(un), 1e-12f);
  float andv = fmaxf(sqrtf(an), 1e-12f);
  ((float2*)(Pu + (size_t)wave * D))[lane] = float2{uv.x / und, uv.y / und};
  ((float2*)(Ps + (size_t)wave * D))[lane] = float2{av.x / andv, av.y / andv};
}

// per-row: ttl = logsumexp_j(dot(p_b,p_j)/0.2); acc += ttl - pos
__global__ __launch_bounds__(256) void k_closs(const float* __restrict__ P, float* __restrict__ acc) {
  __shared__ float prow[D];
  __shared__ float sm[4], ss[4];
  int b = blockIdx.x;
  int tid = threadIdx.x;
  if (tid < D) prow[tid] = P[(size_t)b * D + tid];
  __syncthreads();
  float m = -3.4e38f, s = 0.f;
  for (int j = tid; j < Bc; j += 256) {
    const float4* pj = (const float4*)(P + (size_t)j * D);
    const float4* pr = (const float4*)prow;
    float d = 0.f;
#pragma unroll
    for (int t = 0; t < D / 4; ++t) {
      float4 q = pj[t], p = pr[t];
      d = fmaf(p.x, q.x, d); d = fmaf(p.y, q.y, d);
      d = fmaf(p.z, q.z, d); d = fmaf(p.w, q.w, d);
    }
    d *= 5.0f;  // /C_TEMP
    if (d > m) { s = s * expf(m - d) + 1.0f; m = d; }
    else s += expf(d - m);
  }
  for (int o = 1; o < 64; o <<= 1) {
    float om = __shfl_xor(m, o, 64), os = __shfl_xor(s, o, 64);
    float M = fmaxf(m, om);
    s = s * expf(m - M) + os * expf(om - M);
    m = M;
  }
  int w = tid >> 6;
  if ((tid & 63) == 0) { sm[w] = m; ss[w] = s; }
  __syncthreads();
  if (tid == 0) {
    float M = fmaxf(fmaxf(sm[0], sm[1]), fmaxf(sm[2], sm[3]));
    float S = ss[0] * expf(sm[0] - M) + ss[1] * expf(sm[1] - M) +
              ss[2] * expf(sm[2] - M) + ss[3] * expf(sm[3] - M);
    float ttl = M + logf(S);
    float pos = 0.f;
    for (int t = 0; t < D; ++t) pos = fmaf(prow[t], prow[t], pos);
    pos *= 5.0f;
    atomicAdd(acc, ttl - pos);
  }
}

__global__ void k_final(const float* __restrict__ accs, float* __restrict__ out) {
  if (threadIdx.x == 0 && blockIdx.x == 0) {
    out[0] = accs[0] / (float)Bc;
    out[1] = 0.5f * (accs[1] + accs[2]) / (float)Bc;
  }
}

// ---------------- launch ----------------
extern "C" void kernel_launch(void* const* d_in, const int* in_sizes, int n_in,
                              void* d_out, int out_size, void* d_ws, size_t ws_size,
                              hipStream_t stream) {
  const float* usersF = (const float*)d_in[0];
  const float* streamersF = (const float*)d_in[1];
  const float* videosF = (const float*)d_in[2];
  const float* linW = (const float*)d_in[3];
  const float* linB = (const float*)d_in[4];
  const int* us_row = (const int*)d_in[5];
  const int* us_col = (const int*)d_in[6];
  const float* us_val = (const float*)d_in[7];
  const int* uv_row = (const int*)d_in[8];
  const int* uv_col = (const int*)d_in[9];
  const float* uv_val = (const float*)d_in[10];
  const int* sv_row = (const int*)d_in[11];
  const int* sv_col = (const int*)d_in[12];
  const float* sv_val = (const float*)d_in[13];
  const int* uva_row = (const int*)d_in[14];
  const int* uva_col = (const int*)d_in[15];
  const float* uva_val = (const float*)d_in[16];
  const int* sva_row = (const int*)d_in[17];
  const int* sva_col = (const int*)d_in[18];
  const float* sva_val = (const float*)d_in[19];
  const int* users = (const int*)d_in[20];
  const int* streamers = (const int*)d_in[21];
  const int nnz_us = in_sizes[5], nnz_uv = in_sizes[8], nnz_sv = in_sizes[11];
  const int nnz_uva = in_sizes[14], nnz_sva = in_sizes[17];
  float* out = (float*)d_out;

  float* ws = (float*)d_ws;
  size_t o = 0;
  float* UVm = ws + o; o += (size_t)(NUc + NVc) * D;   // 80000 rows
  float* SVm = ws + o; o += (size_t)(NSc + NVc) * D;   // 40000 rows
  float* USm = ws + o; o += (size_t)(NUc + NSc) * D;   // 60000 rows
  float* UVs = ws + o; o += (size_t)NSc * D;
  float* SVu = ws + o; o += (size_t)NUc * D;
  float* F   = ws + o; o += (size_t)(NUc + NVc) * D;
  float* T   = ws + o; o += (size_t)(NUc + NVc) * D;
  // CSR scratch regions aliased into dead feature space:
  int* regA = (int*)UVm;                         // live before UV concat (US prop)
  int* regB = (int*)SVm;                         // live before SV concat (UV prop + sva agg)
  int* regC = (int*)(UVm + (size_t)NUc * D);     // UVm video half, dead after sva agg
  // loss scratch aliases F (dead after last prop)
  float* Pu = F;
  float* Ps = F + (size_t)Bc * D;
  float* accs = F + (size_t)2 * Bc * D;

  // key derivation (JAX threefry, partitionable fold-in split)
  uint32_t kus[2], kuv[2], ksv[2], kauv[2], kasv[2];
  threefry(0u, 42u, 0u, 0u, kus[0], kus[1]);
  threefry(0u, 42u, 0u, 1u, kuv[0], kuv[1]);
  threefry(0u, 42u, 0u, 2u, ksv[0], ksv[1]);
  threefry(0u, 42u, 0u, 3u, kauv[0], kauv[1]);
  threefry(0u, 42u, 0u, 4u, kasv[0], kasv[1]);
  uint32_t kusL[2][2], kuvL[2][2], ksvL[2][2];
  for (uint32_t i = 0; i < 2; ++i) {
    threefry(kus[0], kus[1], 0u, i, kusL[i][0], kusL[i][1]);
    threefry(kuv[0], kuv[1], 0u, i, kuvL[i][0], kuvL[i][1]);
    threefry(ksv[0], ksv[1], 0u, i, ksvL[i][0], ksvL[i][1]);
  }

  // CSR layout within a region: [cv: 2*nnz ints (int2)] [rp: n+1] [cursor: n]
  auto build_csr = [&](int* region, const int* grow, const int* gcol, const float* gval,
                       int nnz, int n, int2*& cv, int*& rp) {
    cv = (int2*)region;
    rp = region + (size_t)2 * nnz;
    int* cur = rp + (n + 1);
    hipMemsetAsync(rp, 0, (size_t)(n + 1) * sizeof(int), stream);
    k_hist<<<(unsigned)((nnz + 255) / 256), 256, 0, stream>>>(grow, nnz, rp);
    k_scan<<<1, 1024, 0, stream>>>(rp, n + 1);
    k_copy<<<(unsigned)((n + 255) / 256), 256, 0, stream>>>(rp, cur, n);
    k_scatter<<<(unsigned)((nnz + 255) / 256), 256, 0, stream>>>(grow, gcol, gval, nnz, cur, cv);
  };

  auto run_prop = [&](const float* a, int na, const float* b, int nb, int* region,
                      const int* grow, const int* gcol, const float* gval, int nnz,
                      float* acc, const uint32_t (&kL)[2][2]) {
    int n = na + nb;
    int2* cv; int* rp;
    build_csr(region, grow, gcol, gval, nnz, n, cv, rp);
    size_t tot4 = (size_t)n * (D / 4);
    k_concat<<<(unsigned)((tot4 + 255) / 256), 256, 0, stream>>>(a, na, b, nb, F, acc);
    k_gprop<<<(unsigned)((n + 3) / 4), 256, 0, stream>>>(rp, cv, F, T, acc, n, 0.1f, 1.0f,
                                                         kL[0][0], kL[0][1]);
    k_gprop<<<(unsigned)((n + 3) / 4), 256, 0, stream>>>(rp, cv, T, F, acc, n, 0.1f, 3.0f,
                                                         kL[1][0], kL[1][1]);
  };

  auto run_agg = [&](int* region, const int* grow, const int* gcol, const float* gval, int nnz,
                     const float* src, int n_out, float* dst, const uint32_t (&k)[2]) {
    int2* cv; int* rp;
    build_csr(region, grow, gcol, gval, nnz, n_out, cv, rp);
    k_gagg<<<(unsigned)((n_out + 3) / 4), 256, 0, stream>>>(rp, cv, src, dst, n_out, 0.1f,
                                                            k[0], k[1]);
  };

  // US propagate first (CSR in UVm space, dead until UV concat)
  run_prop(usersF, NUc, streamersF, NSc, regA, us_row, us_col, us_val, nnz_us, USm, kusL);
  // UV propagate (CSR in SVm space) ; UV_s aggregate from UVm video half
  run_prop(usersF, NUc, videosF, NVc, regB, uv_row, uv_col, uv_val, nnz_uv, UVm, kuvL);
  run_agg(regB, sva_row, sva_col, sva_val, nnz_sva, UVm + (size_t)NUc * D, NSc, UVs, kasv);
  // SV propagate (CSR in UVm video half, dead now) ; SV_u aggregate from SVm video half
  run_prop(streamersF, NSc, videosF, NVc, regC, sv_row, sv_col, sv_val, nnz_sv, SVm, ksvL);
  run_agg(regC, uva_row, uva_col, uva_val, nnz_uva, SVm + (size_t)NSc * D, NUc, SVu, kauv);
  // MGA attention in-place into USm -> [users_rep ; streamers_rep]
  k_mga<<<(unsigned)((NUc + NSc + 3) / 4), 256, 0, stream>>>(USm, UVm, UVs, SVu, SVm, linW, linB);
  // losses
  hipMemsetAsync(accs, 0, 16 * sizeof(float), stream);
  k_batch<<<(unsigned)((Bc + 3) / 4), 256, 0, stream>>>(USm, users, streamers, Pu, Ps, accs);
  k_closs<<<Bc, 256, 0, stream>>>(Pu, accs + 1);
  k_closs<<<Bc, 256, 0, stream>>>(Ps, accs + 2);
  k_final<<<1, 64, 0, stream>>>(accs, out);
}

// Round 3
// 1490.439 us; speedup vs baseline: 7.9731x; 1.3772x over previous
//
#include <hip/hip_runtime.h>
#include <stdint.h>

#define D 128
constexpr int NUc = 50000, NSc = 10000, NVc = 30000, Bc = 2048;

// ---------------- Threefry-2x32 (JAX) ----------------
__host__ __device__ inline void threefry(uint32_t k0, uint32_t k1, uint32_t x0, uint32_t x1,
                                         uint32_t& o0, uint32_t& o1) {
  uint32_t ks2 = k0 ^ k1 ^ 0x1BD11BDAu;
  uint32_t v0 = x0 + k0, v1 = x1 + k1;
#define TFR(r) { v0 += v1; v1 = (v1 << (r)) | (v1 >> (32 - (r))); v1 ^= v0; }
  TFR(13) TFR(15) TFR(26) TFR(6)   v0 += k1;  v1 += ks2 + 1u;
  TFR(17) TFR(29) TFR(16) TFR(24)  v0 += ks2; v1 += k0 + 2u;
  TFR(13) TFR(15) TFR(26) TFR(6)   v0 += k0;  v1 += k1 + 3u;
  TFR(17) TFR(29) TFR(16) TFR(24)  v0 += k1;  v1 += ks2 + 4u;
  TFR(13) TFR(15) TFR(26) TFR(6)   v0 += ks2; v1 += k0 + 5u;
#undef TFR
  o0 = v0; o1 = v1;
}

__device__ __forceinline__ float unif01(uint32_t k0, uint32_t k1, uint32_t j) {
  uint32_t a, b;
  threefry(k0, k1, 0u, j, a, b);
  uint32_t bits = a ^ b;
  return __uint_as_float(0x3F800000u | (bits >> 9)) - 1.0f;
}

// ---------------- CSR build ----------------
__global__ void k_hist(const int* __restrict__ rows, int nnz, int* __restrict__ counts) {
  int e = blockIdx.x * blockDim.x + threadIdx.x;
  if (e < nnz) atomicAdd(&counts[rows[e] + 1], 1);
}

// two-level scan: per-chunk inclusive scan + block totals
__global__ __launch_bounds__(1024) void k_scan1(int* __restrict__ data, int n,
                                                int* __restrict__ aux) {
  __shared__ int wsum[16];
  int tid = threadIdx.x, lane = tid & 63, w = tid >> 6;
  int i = blockIdx.x * 1024 + tid;
  int v = (i < n) ? data[i] : 0;
  int x = v;
  for (int off = 1; off < 64; off <<= 1) {
    int t = __shfl_up(x, off, 64);
    if (lane >= off) x += t;
  }
  if (lane == 63) wsum[w] = x;
  __syncthreads();
  if (w == 0 && lane < 16) {
    int s = wsum[lane];
    for (int off = 1; off < 16; off <<= 1) {
      int t = __shfl_up(s, off, 64);
      if (lane >= off) s += t;
    }
    wsum[lane] = s;
  }
  __syncthreads();
  int woff = (w > 0) ? wsum[w - 1] : 0;
  if (i < n) data[i] = x + woff;
  if (tid == 1023) aux[blockIdx.x] = x + woff;  // block total (padding v=0 safe)
}

__global__ void k_scan2(int* __restrict__ aux, int nb) {
  int lane = threadIdx.x;  // 64 threads
  int carry = 0;
  for (int base = 0; base < nb; base += 64) {
    int i = base + lane;
    int v = (i < nb) ? aux[i] : 0;
    for (int off = 1; off < 64; off <<= 1) {
      int t = __shfl_up(v, off, 64);
      if (lane >= off) v += t;
    }
    if (i < nb) aux[i] = v + carry;
    carry += __shfl(v, 63, 64);
  }
}

__global__ __launch_bounds__(1024) void k_scan3(int* __restrict__ data, int n,
                                                const int* __restrict__ aux) {
  int blk = blockIdx.x;
  if (blk == 0) return;
  int i = blk * 1024 + threadIdx.x;
  if (i < n) data[i] += aux[blk - 1];
}

__global__ void k_copy(const int* __restrict__ src, int* __restrict__ dst, int n) {
  int i = blockIdx.x * blockDim.x + threadIdx.x;
  if (i < n) dst[i] = src[i];
}

__global__ void k_scatter(const int* __restrict__ rows, const int* __restrict__ cols,
                          const float* __restrict__ vals, int nnz, int* __restrict__ cursor,
                          int2* __restrict__ cv) {
  int e = blockIdx.x * blockDim.x + threadIdx.x;
  if (e >= nnz) return;
  int pos = atomicAdd(&cursor[rows[e]], 1);
  cv[pos] = make_int2(cols[e], __float_as_int(vals[e]));
}

// ---------------- feature kernels ----------------
__global__ void k_concat(const float* __restrict__ a, int na, const float* __restrict__ b, int nb,
                         float* __restrict__ feats, float* __restrict__ acc) {
  size_t idx = (size_t)blockIdx.x * blockDim.x + threadIdx.x;  // float4 units
  size_t tot = (size_t)(na + nb) * (D / 4);
  if (idx >= tot) return;
  size_t aEnd = (size_t)na * (D / 4);
  float4 v = (idx < aEnd) ? ((const float4*)a)[idx] : ((const float4*)b)[idx - aEnd];
  ((float4*)feats)[idx] = v;
  ((float4*)acc)[idx] = v;
}

// gather SpMM (wave per row) + fused propagate-noise epilogue
__global__ void k_gprop(const int* __restrict__ rp, const int2* __restrict__ cv,
                        const float* __restrict__ src, float* __restrict__ dst,
                        float* __restrict__ acc, int nrows, float eps, float div,
                        unsigned k0, unsigned k1) {
  int gid = blockIdx.x * blockDim.x + threadIdx.x;
  int r = gid >> 6, lane = gid & 63;
  if (r >= nrows) return;
  int s = rp[r], e = rp[r + 1];
  const float2* sp = (const float2*)src;
  float fx = 0.f, fy = 0.f;
  for (int k = s; k < e; ++k) {
    int2 p = cv[k];
    float v = __int_as_float(p.y);
    float2 xv = sp[(size_t)p.x * (D / 2) + lane];
    fx = fmaf(v, xv.x, fx);
    fy = fmaf(v, xv.y, fy);
  }
  size_t base = (size_t)r * D + lane * 2;
  uint32_t j0 = (uint32_t)base;
  float u0 = unif01(k0, k1, j0);
  float u1 = unif01(k0, k1, j0 + 1u);
  float s2 = u0 * u0 + u1 * u1;
  for (int m = 1; m < 64; m <<= 1) s2 += __shfl_xor(s2, m, 64);
  float nn = fmaxf(sqrtf(s2), 1e-12f);
  float sg0 = (fx > 0.f) ? 1.f : ((fx < 0.f) ? -1.f : 0.f);
  float sg1 = (fy > 0.f) ? 1.f : ((fy < 0.f) ? -1.f : 0.f);
  float nf0 = fx + sg0 * (u0 / nn) * eps;
  float nf1 = fy + sg1 * (u1 / nn) * eps;
  float fs = nf0 * nf0 + nf1 * nf1;
  for (int m = 1; m < 64; m <<= 1) fs += __shfl_xor(fs, m, 64);
  float fn = fmaxf(sqrtf(fs), 1e-12f);
  float2 a = *(const float2*)(acc + base);
  a.x = (a.x + nf0 / fn) / div;
  a.y = (a.y + nf1 / fn) / div;
  *(float2*)(acc + base) = a;
  *(float2*)(dst + base) = float2{nf0, nf1};
}

// gather SpMM (wave per row) + fused aggregate-noise epilogue
__global__ void k_gagg(const int* __restrict__ rp, const int2* __restrict__ cv,
                       const float* __restrict__ src, float* __restrict__ dst,
                       int nrows, float eps, unsigned k0, unsigned k1) {
  int gid = blockIdx.x * blockDim.x + threadIdx.x;
  int r = gid >> 6, lane = gid & 63;
  if (r >= nrows) return;
  int s = rp[r], e = rp[r + 1];
  const float2* sp = (const float2*)src;
  float fx = 0.f, fy = 0.f;
  for (int k = s; k < e; ++k) {
    int2 p = cv[k];
    float v = __int_as_float(p.y);
    float2 xv = sp[(size_t)p.x * (D / 2) + lane];
    fx = fmaf(v, xv.x, fx);
    fy = fmaf(v, xv.y, fy);
  }
  size_t base = (size_t)r * D + lane * 2;
  uint32_t j0 = (uint32_t)base;
  float u0 = unif01(k0, k1, j0);
  float u1 = unif01(k0, k1, j0 + 1u);
  float s2 = u0 * u0 + u1 * u1;
  for (int m = 1; m < 64; m <<= 1) s2 += __shfl_xor(s2, m, 64);
  float nn = fmaxf(sqrtf(s2), 1e-12f);
  float sg0 = (fx > 0.f) ? 1.f : ((fx < 0.f) ? -1.f : 0.f);
  float sg1 = (fy > 0.f) ? 1.f : ((fy < 0.f) ? -1.f : 0.f);
  *(float2*)(dst + base) = float2{fx + sg0 * (u0 / nn) * eps, fy + sg1 * (u1 / nn) * eps};
}

// attention over 3 embeddings, in-place into e0buf
__global__ void k_mga(float* __restrict__ e0buf, const float* __restrict__ UVm,
                      const float* __restrict__ UVs, const float* __restrict__ SVu,
                      const float* __restrict__ SVm, const float* __restrict__ w,
                      const float* __restrict__ bptr) {
  int gid = blockIdx.x * blockDim.x + threadIdx.x;
  int wave = gid >> 6, lane = gid & 63;
  int n = NUc + NSc;
  if (wave >= n) return;
  const float* e1 = (wave < NUc) ? (UVm + (size_t)wave * D) : (UVs + (size_t)(wave - NUc) * D);
  const float* e2 = (wave < NUc) ? (SVu + (size_t)wave * D) : (SVm + (size_t)(wave - NUc) * D);
  float* e0 = e0buf + (size_t)wave * D;
  int c = lane * 2;
  float2 v0 = *(const float2*)(e0 + c);
  float2 v1 = *(const float2*)(e1 + c);
  float2 v2 = *(const float2*)(e2 + c);
  float2 wl = *(const float2*)(w + c);
  float2 wh = *(const float2*)(w + D + c);
  float d00 = v0.x * wl.x + v0.y * wl.y;
  float c0 = v0.x * wh.x + v0.y * wh.y;
  float c1 = v1.x * wh.x + v1.y * wh.y;
  float c2 = v2.x * wh.x + v2.y * wh.y;
  for (int m = 1; m < 64; m <<= 1) {
    d00 += __shfl_xor(d00, m, 64);
    c0 += __shfl_xor(c0, m, 64);
    c1 += __shfl_xor(c1, m, 64);
    c2 += __shfl_xor(c2, m, 64);
  }
  float b = bptr[0];
  float l0 = d00 + c0 + b, l1 = d00 + c1 + b, l2v = d00 + c2 + b;
  float mx = fmaxf(l0, fmaxf(l1, l2v));
  float a0 = expf(l0 - mx), a1 = expf(l1 - mx), a2 = expf(l2v - mx);
  float s = a0 + a1 + a2;
  a0 /= s; a1 /= s; a2 /= s;
  float2 o;
  o.x = a0 * v0.x + a1 * v1.x + a2 * v2.x;
  o.y = a0 * v0.y + a1 * v1.y + a2 * v2.y;
  *(float2*)(e0 + c) = o;
}

// gather batch rows: BPR accumulation + normalized P rows
__global__ void k_batch(const float* __restrict__ reps, const int* __restrict__ users,
                        const int* __restrict__ streamers, float* __restrict__ Pu,
                        float* __restrict__ Ps, float* __restrict__ accs) {
  int gid = blockIdx.x * blockDim.x + threadIdx.x;
  int wave = gid >> 6, lane = gid & 63;
  if (wave >= Bc) return;
  int u = users[wave];
  int s0 = streamers[wave * 2], s1 = streamers[wave * 2 + 1];
  const float2* ur = (const float2*)(reps + (size_t)u * D);
  const float2* ar = (const float2*)(reps + (size_t)(NUc + s0) * D);
  const float2* cr = (const float2*)(reps + (size_t)(NUc + s1) * D);
  float2 uv = ur[lane], av = ar[lane], cv = cr[lane];
  float p0 = uv.x * av.x + uv.y * av.y;
  float p1 = uv.x * cv.x + uv.y * cv.y;
  float un = uv.x * uv.x + uv.y * uv.y;
  float an = av.x * av.x + av.y * av.y;
  for (int m = 1; m < 64; m <<= 1) {
    p0 += __shfl_xor(p0, m, 64);
    p1 += __shfl_xor(p1, m, 64);
    un += __shfl_xor(un, m, 64);
    an += __shfl_xor(an, m, 64);
  }
  if (lane == 0) {
    float t = p0 - p1;
    float term = fmaxf(-t, 0.f) + log1pf(expf(-fabsf(t)));  // -log_sigmoid(t)
    atomicAdd(&accs[0], term);
  }
  float und = fmaxf(sqrtf(un), 1e-12f);
  float andv = fmaxf(sqrtf(an), 1e-12f);
  ((float2*)(Pu + (size_t)wave * D))[lane] = float2{uv.x / und, uv.y / und};
  ((float2*)(Ps + (size_t)wave * D))[lane] = float2{av.x / andv, av.y / andv};
}

// contrastive GEMM: G = P@P^T, S[b] += sum_j exp(5*G[b][j])  (no max needed: |logit|<=5)
// block: 256 thr (16x16), tile 32(b) x 64(j), micro 2x4, j-split over gridDim.y
__global__ __launch_bounds__(256) void k_cgemm(const float* __restrict__ Pu,
                                               const float* __restrict__ Ps,
                                               float* __restrict__ Su,
                                               float* __restrict__ Ss) {
  const float* P = blockIdx.z ? Ps : Pu;
  float* S = blockIdx.z ? Ss : Su;
  __shared__ float A[32][132];    // [row][k], pad keeps 16B align, conflict-free reads
  __shared__ float BT[128][68];   // [k][col], pad 68
  int tid = threadIdx.x;
  int tx = tid & 15, ty = tid >> 4;
  int brow0 = blockIdx.x * 32;
  int j0 = blockIdx.y * 512;
  // A tile: 32x128 = 1024 float4, 4 per thread
#pragma unroll
  for (int i = 0; i < 4; ++i) {
    int idx = tid + i * 256;
    int r = idx >> 5, c4 = idx & 31;
    float4 v = ((const float4*)(P + (size_t)(brow0 + r) * D))[c4];
    *(float4*)&A[r][c4 * 4] = v;
  }
  float s[2] = {0.f, 0.f};
  for (int jt = 0; jt < 8; ++jt) {
    __syncthreads();
    // B tile (64 rows) transposed: 2048 float4, 8 per thread
#pragma unroll
    for (int i = 0; i < 8; ++i) {
      int idx = tid + i * 256;
      int r = idx >> 5, c4 = idx & 31;
      float4 v = ((const float4*)(P + (size_t)(j0 + jt * 64 + r) * D))[c4];
      BT[c4 * 4 + 0][r] = v.x;
      BT[c4 * 4 + 1][r] = v.y;
      BT[c4 * 4 + 2][r] = v.z;
      BT[c4 * 4 + 3][r] = v.w;
    }
    __syncthreads();
    float acc[2][4] = {};
    for (int k = 0; k < 128; k += 4) {
      float4 a0 = *(const float4*)&A[ty * 2 + 0][k];
      float4 a1 = *(const float4*)&A[ty * 2 + 1][k];
      float4 b0 = *(const float4*)&BT[k + 0][tx * 4];
      float4 b1 = *(const float4*)&BT[k + 1][tx * 4];
      float4 b2 = *(const float4*)&BT[k + 2][tx * 4];
      float4 b3 = *(const float4*)&BT[k + 3][tx * 4];
      acc[0][0] = fmaf(a0.x, b0.x, acc[0][0]); acc[0][1] = fmaf(a0.x, b0.y, acc[0][1]);
      acc[0][2] = fmaf(a0.x, b0.z, acc[0][2]); acc[0][3] = fmaf(a0.x, b0.w, acc[0][3]);
      acc[1][0] = fmaf(a1.x, b0.x, acc[1][0]); acc[1][1] = fmaf(a1.x, b0.y, acc[1][1]);
      acc[1][2] = fmaf(a1.x, b0.z, acc[1][2]); acc[1][3] = fmaf(a1.x, b0.w, acc[1][3]);
      acc[0][0] = fmaf(a0.y, b1.x, acc[0][0]); acc[0][1] = fmaf(a0.y, b1.y, acc[0][1]);
      acc[0][2] = fmaf(a0.y, b1.z, acc[0][2]); acc[0][3] = fmaf(a0.y, b1.w, acc[0][3]);
      acc[1][0] = fmaf(a1.y, b1.x, acc[1][0]); acc[1][1] = fmaf(a1.y, b1.y, acc[1][1]);
      acc[1][2] = fmaf(a1.y, b1.z, acc[1][2]); acc[1][3] = fmaf(a1.y, b1.w, acc[1][3]);
      acc[0][0] = fmaf(a0.z, b2.x, acc[0][0]); acc[0][1] = fmaf(a0.z, b2.y, acc[0][1]);
      acc[0][2] = fmaf(a0.z, b2.z, acc[0][2]); acc[0][3] = fmaf(a0.z, b2.w, acc[0][3]);
      acc[1][0] = fmaf(a1.z, b2.x, acc[1][0]); acc[1][1] = fmaf(a1.z, b2.y, acc[1][1]);
      acc[1][2] = fmaf(a1.z, b2.z, acc[1][2]); acc[1][3] = fmaf(a1.z, b2.w, acc[1][3]);
      acc[0][0] = fmaf(a0.w, b3.x, acc[0][0]); acc[0][1] = fmaf(a0.w, b3.y, acc[0][1]);
      acc[0][2] = fmaf(a0.w, b3.z, acc[0][2]); acc[0][3] = fmaf(a0.w, b3.w, acc[0][3]);
      acc[1][0] = fmaf(a1.w, b3.x, acc[1][0]); acc[1][1] = fmaf(a1.w, b3.y, acc[1][1]);
      acc[1][2] = fmaf(a1.w, b3.z, acc[1][2]); acc[1][3] = fmaf(a1.w, b3.w, acc[1][3]);
    }
#pragma unroll
    for (int i = 0; i < 2; ++i)
#pragma unroll
      for (int jj = 0; jj < 4; ++jj) s[i] += __expf(5.0f * acc[i][jj]);
  }
  // reduce s over the 16 tx lanes (contiguous within wave)
#pragma unroll
  for (int i = 0; i < 2; ++i) {
    for (int off = 1; off < 16; off <<= 1) s[i] += __shfl_xor(s[i], off, 64);
    if (tx == 0) atomicAdd(&S[brow0 + ty * 2 + i], s[i]);
  }
}

// finish: acc += log(S[b]) - 5*|p_b|^2  (one wave per row)
__global__ void k_cfinal(const float* __restrict__ Pu, const float* __restrict__ Ps,
                         const float* __restrict__ Su, const float* __restrict__ Ss,
                         float* __restrict__ accs) {
  int gid = blockIdx.x * blockDim.x + threadIdx.x;
  int wave = gid >> 6, lane = gid & 63;
  if (wave >= 2 * Bc) return;
  int loss = wave >> 11, b = wave & (Bc - 1);
  const float* P = loss ? Ps : Pu;
  const float* S = loss ? Ss : Su;
  float2 p = ((const float2*)(P + (size_t)b * D))[lane];
  float pos = p.x * p.x + p.y * p.y;
  for (int m = 1; m < 64; m <<= 1) pos += __shfl_xor(pos, m, 64);
  if (lane == 0) atomicAdd(&accs[1 + loss], logf(S[b]) - 5.0f * pos);
}

__global__ void k_final(const float* __restrict__ accs, float* __restrict__ out) {
  if (threadIdx.x == 0 && blockIdx.x == 0) {
    out[0] = accs[0] / (float)Bc;
    out[1] = 0.5f * (accs[1] + accs[2]) / (float)Bc;
  }
}

// ---------------- launch ----------------
extern "C" void kernel_launch(void* const* d_in, const int* in_sizes, int n_in,
                              void* d_out, int out_size, void* d_ws, size_t ws_size,
                              hipStream_t stream) {
  const float* usersF = (const float*)d_in[0];
  const float* streamersF = (const float*)d_in[1];
  const float* videosF = (const float*)d_in[2];
  const float* linW = (const float*)d_in[3];
  const float* linB = (const float*)d_in[4];
  const int* us_row = (const int*)d_in[5];
  const int* us_col = (const int*)d_in[6];
  const float* us_val = (const float*)d_in[7];
  const int* uv_row = (const int*)d_in[8];
  const int* uv_col = (const int*)d_in[9];
  const float* uv_val = (const float*)d_in[10];
  const int* sv_row = (const int*)d_in[11];
  const int* sv_col = (const int*)d_in[12];
  const float* sv_val = (const float*)d_in[13];
  const int* uva_row = (const int*)d_in[14];
  const int* uva_col = (const int*)d_in[15];
  const float* uva_val = (const float*)d_in[16];
  const int* sva_row = (const int*)d_in[17];
  const int* sva_col = (const int*)d_in[18];
  const float* sva_val = (const float*)d_in[19];
  const int* users = (const int*)d_in[20];
  const int* streamers = (const int*)d_in[21];
  const int nnz_us = in_sizes[5], nnz_uv = in_sizes[8], nnz_sv = in_sizes[11];
  const int nnz_uva = in_sizes[14], nnz_sva = in_sizes[17];
  float* out = (float*)d_out;

  float* ws = (float*)d_ws;
  size_t o = 0;
  float* UVm = ws + o; o += (size_t)(NUc + NVc) * D;   // 80000 rows
  float* SVm = ws + o; o += (size_t)(NSc + NVc) * D;   // 40000 rows
  float* USm = ws + o; o += (size_t)(NUc + NSc) * D;   // 60000 rows
  float* UVs = ws + o; o += (size_t)NSc * D;
  float* SVu = ws + o; o += (size_t)NUc * D;
  float* F   = ws + o; o += (size_t)(NUc + NVc) * D;
  float* T   = ws + o; o += (size_t)(NUc + NVc) * D;
  // CSR scratch regions aliased into dead feature space:
  int* regA = (int*)UVm;                         // live before UV concat (US prop)
  int* regB = (int*)SVm;                         // live before SV concat (UV prop + sva agg)
  int* regC = (int*)(UVm + (size_t)NUc * D);     // UVm video half, dead after sva agg
  // loss scratch aliases F (dead after last prop)
  float* Pu = F;
  float* Ps = F + (size_t)Bc * D;
  float* accs = F + (size_t)2 * Bc * D;          // [0..15] scalars
  float* Su = accs + 16;                         // 2048
  float* Ss = Su + Bc;                           // 2048

  // key derivation (JAX threefry, partitionable fold-in split)
  uint32_t kus[2], kuv[2], ksv[2], kauv[2], kasv[2];
  threefry(0u, 42u, 0u, 0u, kus[0], kus[1]);
  threefry(0u, 42u, 0u, 1u, kuv[0], kuv[1]);
  threefry(0u, 42u, 0u, 2u, ksv[0], ksv[1]);
  threefry(0u, 42u, 0u, 3u, kauv[0], kauv[1]);
  threefry(0u, 42u, 0u, 4u, kasv[0], kasv[1]);
  uint32_t kusL[2][2], kuvL[2][2], ksvL[2][2];
  for (uint32_t i = 0; i < 2; ++i) {
    threefry(kus[0], kus[1], 0u, i, kusL[i][0], kusL[i][1]);
    threefry(kuv[0], kuv[1], 0u, i, kuvL[i][0], kuvL[i][1]);
    threefry(ksv[0], ksv[1], 0u, i, ksvL[i][0], ksvL[i][1]);
  }

  // CSR region layout: [cv: 2*nnz ints] [rp: n+1] [cursor: n] [aux: <=128]
  auto build_csr = [&](int* region, const int* grow, const int* gcol, const float* gval,
                       int nnz, int n, int2*& cv, int*& rp) {
    cv = (int2*)region;
    rp = region + (size_t)2 * nnz;
    int* cur = rp + (n + 1);
    int* aux = cur + n;
    int nsc = n + 1;
    int nb = (nsc + 1023) / 1024;
    hipMemsetAsync(rp, 0, (size_t)nsc * sizeof(int), stream);
    k_hist<<<(unsigned)((nnz + 255) / 256), 256, 0, stream>>>(grow, nnz, rp);
    k_scan1<<<(unsigned)nb, 1024, 0, stream>>>(rp, nsc, aux);
    k_scan2<<<1, 64, 0, stream>>>(aux, nb);
    k_scan3<<<(unsigned)nb, 1024, 0, stream>>>(rp, nsc, aux);
    k_copy<<<(unsigned)((n + 255) / 256), 256, 0, stream>>>(rp, cur, n);
    k_scatter<<<(unsigned)((nnz + 255) / 256), 256, 0, stream>>>(grow, gcol, gval, nnz, cur, cv);
  };

  auto run_prop = [&](const float* a, int na, const float* b, int nb, int* region,
                      const int* grow, const int* gcol, const float* gval, int nnz,
                      float* acc, const uint32_t (&kL)[2][2]) {
    int n = na + nb;
    int2* cv; int* rp;
    build_csr(region, grow, gcol, gval, nnz, n, cv, rp);
    size_t tot4 = (size_t)n * (D / 4);
    k_concat<<<(unsigned)((tot4 + 255) / 256), 256, 0, stream>>>(a, na, b, nb, F, acc);
    k_gprop<<<(unsigned)((n + 3) / 4), 256, 0, stream>>>(rp, cv, F, T, acc, n, 0.1f, 1.0f,
                                                         kL[0][0], kL[0][1]);
    k_gprop<<<(unsigned)((n + 3) / 4), 256, 0, stream>>>(rp, cv, T, F, acc, n, 0.1f, 3.0f,
                                                         kL[1][0], kL[1][1]);
  };

  auto run_agg = [&](int* region, const int* grow, const int* gcol, const float* gval, int nnz,
                     const float* src, int n_out, float* dst, const uint32_t (&k)[2]) {
    int2* cv; int* rp;
    build_csr(region, grow, gcol, gval, nnz, n_out, cv, rp);
    k_gagg<<<(unsigned)((n_out + 3) / 4), 256, 0, stream>>>(rp, cv, src, dst, n_out, 0.1f,
                                                            k[0], k[1]);
  };

  // US propagate first (CSR in UVm space, dead until UV concat)
  run_prop(usersF, NUc, streamersF, NSc, regA, us_row, us_col, us_val, nnz_us, USm, kusL);
  // UV propagate (CSR in SVm space) ; UV_s aggregate from UVm video half
  run_prop(usersF, NUc, videosF, NVc, regB, uv_row, uv_col, uv_val, nnz_uv, UVm, kuvL);
  run_agg(regB, sva_row, sva_col, sva_val, nnz_sva, UVm + (size_t)NUc * D, NSc, UVs, kasv);
  // SV propagate (CSR in UVm video half, dead now) ; SV_u aggregate from SVm video half
  run_prop(streamersF, NSc, videosF, NVc, regC, sv_row, sv_col, sv_val, nnz_sv, SVm, ksvL);
  run_agg(regC, uva_row, uva_col, uva_val, nnz_uva, SVm + (size_t)NSc * D, NUc, SVu, kauv);
  // MGA attention in-place into USm -> [users_rep ; streamers_rep]
  k_mga<<<(unsigned)((NUc + NSc + 3) / 4), 256, 0, stream>>>(USm, UVm, UVs, SVu, SVm, linW, linB);
  // losses
  hipMemsetAsync(accs, 0, (16 + 2 * Bc) * sizeof(float), stream);
  k_batch<<<(unsigned)((Bc + 3) / 4), 256, 0, stream>>>(USm, users, streamers, Pu, Ps, accs);
  k_cgemm<<<dim3(Bc / 32, 4, 2), 256, 0, stream>>>(Pu, Ps, Su, Ss);
  k_cfinal<<<(unsigned)((2 * Bc + 3) / 4), 256, 0, stream>>>(Pu, Ps, Su, Ss, accs);
  k_final<<<1, 64, 0, stream>>>(accs, out);
}

// Round 4
// 1217.061 us; speedup vs baseline: 9.7641x; 1.2246x over previous
//
#include <hip/hip_runtime.h>
#include <stdint.h>

#define D 128
constexpr int NUc = 50000, NSc = 10000, NVc = 30000, Bc = 2048;

typedef _Float16 h2v __attribute__((ext_vector_type(2)));
typedef _Float16 h4v __attribute__((ext_vector_type(4)));

// ---------------- Threefry-2x32 (JAX) ----------------
__host__ __device__ inline void threefry(uint32_t k0, uint32_t k1, uint32_t x0, uint32_t x1,
                                         uint32_t& o0, uint32_t& o1) {
  uint32_t ks2 = k0 ^ k1 ^ 0x1BD11BDAu;
  uint32_t v0 = x0 + k0, v1 = x1 + k1;
#define TFR(r) { v0 += v1; v1 = (v1 << (r)) | (v1 >> (32 - (r))); v1 ^= v0; }
  TFR(13) TFR(15) TFR(26) TFR(6)   v0 += k1;  v1 += ks2 + 1u;
  TFR(17) TFR(29) TFR(16) TFR(24)  v0 += ks2; v1 += k0 + 2u;
  TFR(13) TFR(15) TFR(26) TFR(6)   v0 += k0;  v1 += k1 + 3u;
  TFR(17) TFR(29) TFR(16) TFR(24)  v0 += k1;  v1 += ks2 + 4u;
  TFR(13) TFR(15) TFR(26) TFR(6)   v0 += ks2; v1 += k0 + 5u;
#undef TFR
  o0 = v0; o1 = v1;
}

__device__ __forceinline__ float unif01(uint32_t k0, uint32_t k1, uint32_t j) {
  uint32_t a, b;
  threefry(k0, k1, 0u, j, a, b);
  uint32_t bits = a ^ b;
  return __uint_as_float(0x3F800000u | (bits >> 9)) - 1.0f;
}

// ---------------- CSR build ----------------
__global__ void k_hist(const int* __restrict__ rows, int nnz, int* __restrict__ counts) {
  int e = blockIdx.x * blockDim.x + threadIdx.x;
  if (e < nnz) atomicAdd(&counts[rows[e] + 1], 1);
}

__global__ __launch_bounds__(1024) void k_scan1(int* __restrict__ data, int n,
                                                int* __restrict__ aux) {
  __shared__ int wsum[16];
  int tid = threadIdx.x, lane = tid & 63, w = tid >> 6;
  int i = blockIdx.x * 1024 + tid;
  int v = (i < n) ? data[i] : 0;
  int x = v;
  for (int off = 1; off < 64; off <<= 1) {
    int t = __shfl_up(x, off, 64);
    if (lane >= off) x += t;
  }
  if (lane == 63) wsum[w] = x;
  __syncthreads();
  if (w == 0 && lane < 16) {
    int s = wsum[lane];
    for (int off = 1; off < 16; off <<= 1) {
      int t = __shfl_up(s, off, 64);
      if (lane >= off) s += t;
    }
    wsum[lane] = s;
  }
  __syncthreads();
  int woff = (w > 0) ? wsum[w - 1] : 0;
  if (i < n) data[i] = x + woff;
  if (tid == 1023) aux[blockIdx.x] = x + woff;
}

__global__ void k_scan2(int* __restrict__ aux, int nb) {
  int lane = threadIdx.x;  // 64
  int carry = 0;
  for (int base = 0; base < nb; base += 64) {
    int i = base + lane;
    int v = (i < nb) ? aux[i] : 0;
    for (int off = 1; off < 64; off <<= 1) {
      int t = __shfl_up(v, off, 64);
      if (lane >= off) v += t;
    }
    if (i < nb) aux[i] = v + carry;
    carry += __shfl(v, 63, 64);
  }
}

__global__ __launch_bounds__(1024) void k_scan3(int* __restrict__ data, int n,
                                                const int* __restrict__ aux) {
  int blk = blockIdx.x;
  if (blk == 0) return;
  int i = blk * 1024 + threadIdx.x;
  if (i < n) data[i] += aux[blk - 1];
}

__global__ void k_copy(const int* __restrict__ src, int* __restrict__ dst, int n) {
  int i = blockIdx.x * blockDim.x + threadIdx.x;
  if (i < n) dst[i] = src[i];
}

__global__ void k_scatter(const int* __restrict__ rows, const int* __restrict__ cols,
                          const float* __restrict__ vals, int nnz, int* __restrict__ cursor,
                          int2* __restrict__ cv) {
  int e = blockIdx.x * blockDim.x + threadIdx.x;
  if (e >= nnz) return;
  int pos = atomicAdd(&cursor[rows[e]], 1);
  cv[pos] = make_int2(cols[e], __float_as_int(vals[e]));
}

// ---------------- feature kernels ----------------
__global__ void k_concat(const float* __restrict__ a, int na, const float* __restrict__ b, int nb,
                         _Float16* __restrict__ hF, float* __restrict__ acc) {
  size_t idx = (size_t)blockIdx.x * blockDim.x + threadIdx.x;  // float4 units
  size_t tot = (size_t)(na + nb) * (D / 4);
  if (idx >= tot) return;
  size_t aEnd = (size_t)na * (D / 4);
  float4 v = (idx < aEnd) ? ((const float4*)a)[idx] : ((const float4*)b)[idx - aEnd];
  ((float4*)acc)[idx] = v;
  h4v h = {(_Float16)v.x, (_Float16)v.y, (_Float16)v.z, (_Float16)v.w};
  ((h4v*)hF)[idx] = h;
}

// gather SpMM (wave per row, fp16 src) + fused propagate-noise epilogue
__global__ void k_gprop(const int* __restrict__ rp, const int2* __restrict__ cv,
                        const _Float16* __restrict__ hsrc, _Float16* __restrict__ hdst,
                        float* __restrict__ acc, _Float16* __restrict__ meanh,
                        int nrows, float eps, float div, unsigned k0, unsigned k1) {
  int gid = blockIdx.x * blockDim.x + threadIdx.x;
  int r = gid >> 6, lane = gid & 63;
  if (r >= nrows) return;
  int s = rp[r], e = rp[r + 1];
  const h2v* sp = (const h2v*)hsrc;
  float fx = 0.f, fy = 0.f;
  int k = s;
  for (; k + 1 < e; k += 2) {
    int2 p0 = cv[k];
    int2 p1 = cv[k + 1];
    h2v x0 = sp[(size_t)p0.x * (D / 2) + lane];
    h2v x1 = sp[(size_t)p1.x * (D / 2) + lane];
    float v0 = __int_as_float(p0.y), v1 = __int_as_float(p1.y);
    fx = fmaf(v0, (float)x0.x, fx); fy = fmaf(v0, (float)x0.y, fy);
    fx = fmaf(v1, (float)x1.x, fx); fy = fmaf(v1, (float)x1.y, fy);
  }
  if (k < e) {
    int2 p = cv[k];
    h2v xv = sp[(size_t)p.x * (D / 2) + lane];
    float v = __int_as_float(p.y);
    fx = fmaf(v, (float)xv.x, fx); fy = fmaf(v, (float)xv.y, fy);
  }
  size_t base = (size_t)r * D + lane * 2;
  uint32_t j0 = (uint32_t)base;
  float u0 = unif01(k0, k1, j0);
  float u1 = unif01(k0, k1, j0 + 1u);
  float s2 = u0 * u0 + u1 * u1;
  for (int m = 1; m < 64; m <<= 1) s2 += __shfl_xor(s2, m, 64);
  float nn = fmaxf(sqrtf(s2), 1e-12f);
  float sg0 = (fx > 0.f) ? 1.f : ((fx < 0.f) ? -1.f : 0.f);
  float sg1 = (fy > 0.f) ? 1.f : ((fy < 0.f) ? -1.f : 0.f);
  float nf0 = fx + sg0 * (u0 / nn) * eps;
  float nf1 = fy + sg1 * (u1 / nn) * eps;
  float fs = nf0 * nf0 + nf1 * nf1;
  for (int m = 1; m < 64; m <<= 1) fs += __shfl_xor(fs, m, 64);
  float fn = fmaxf(sqrtf(fs), 1e-12f);
  float2 a = *(const float2*)(acc + base);
  a.x = (a.x + nf0 / fn) / div;
  a.y = (a.y + nf1 / fn) / div;
  *(float2*)(acc + base) = a;
  ((h2v*)hdst)[base >> 1] = h2v{(_Float16)nf0, (_Float16)nf1};
  if (meanh) ((h2v*)meanh)[base >> 1] = h2v{(_Float16)a.x, (_Float16)a.y};
}

// gather SpMM (wave per row, fp16 src) + fused aggregate-noise epilogue (f32 out)
__global__ void k_gagg(const int* __restrict__ rp, const int2* __restrict__ cv,
                       const _Float16* __restrict__ hsrc, float* __restrict__ dst,
                       int nrows, float eps, unsigned k0, unsigned k1) {
  int gid = blockIdx.x * blockDim.x + threadIdx.x;
  int r = gid >> 6, lane = gid & 63;
  if (r >= nrows) return;
  int s = rp[r], e = rp[r + 1];
  const h2v* sp = (const h2v*)hsrc;
  float fx = 0.f, fy = 0.f;
  int k = s;
  for (; k + 1 < e; k += 2) {
    int2 p0 = cv[k];
    int2 p1 = cv[k + 1];
    h2v x0 = sp[(size_t)p0.x * (D / 2) + lane];
    h2v x1 = sp[(size_t)p1.x * (D / 2) + lane];
    float v0 = __int_as_float(p0.y), v1 = __int_as_float(p1.y);
    fx = fmaf(v0, (float)x0.x, fx); fy = fmaf(v0, (float)x0.y, fy);
    fx = fmaf(v1, (float)x1.x, fx); fy = fmaf(v1, (float)x1.y, fy);
  }
  if (k < e) {
    int2 p = cv[k];
    h2v xv = sp[(size_t)p.x * (D / 2) + lane];
    float v = __int_as_float(p.y);
    fx = fmaf(v, (float)xv.x, fx); fy = fmaf(v, (float)xv.y, fy);
  }
  size_t base = (size_t)r * D + lane * 2;
  uint32_t j0 = (uint32_t)base;
  float u0 = unif01(k0, k1, j0);
  float u1 = unif01(k0, k1, j0 + 1u);
  float s2 = u0 * u0 + u1 * u1;
  for (int m = 1; m < 64; m <<= 1) s2 += __shfl_xor(s2, m, 64);
  float nn = fmaxf(sqrtf(s2), 1e-12f);
  float sg0 = (fx > 0.f) ? 1.f : ((fx < 0.f) ? -1.f : 0.f);
  float sg1 = (fy > 0.f) ? 1.f : ((fy < 0.f) ? -1.f : 0.f);
  *(float2*)(dst + base) = float2{fx + sg0 * (u0 / nn) * eps, fy + sg1 * (u1 / nn) * eps};
}

// attention over 3 embeddings, in-place into e0buf
__global__ void k_mga(float* __restrict__ e0buf, const float* __restrict__ UVm,
                      const float* __restrict__ UVs, const float* __restrict__ SVu,
                      const float* __restrict__ SVm, const float* __restrict__ w,
                      const float* __restrict__ bptr) {
  int gid = blockIdx.x * blockDim.x + threadIdx.x;
  int wave = gid >> 6, lane = gid & 63;
  int n = NUc + NSc;
  if (wave >= n) return;
  const float* e1 = (wave < NUc) ? (UVm + (size_t)wave * D) : (UVs + (size_t)(wave - NUc) * D);
  const float* e2 = (wave < NUc) ? (SVu + (size_t)wave * D) : (SVm + (size_t)(wave - NUc) * D);
  float* e0 = e0buf + (size_t)wave * D;
  int c = lane * 2;
  float2 v0 = *(const float2*)(e0 + c);
  float2 v1 = *(const float2*)(e1 + c);
  float2 v2 = *(const float2*)(e2 + c);
  float2 wl = *(const float2*)(w + c);
  float2 wh = *(const float2*)(w + D + c);
  float d00 = v0.x * wl.x + v0.y * wl.y;
  float c0 = v0.x * wh.x + v0.y * wh.y;
  float c1 = v1.x * wh.x + v1.y * wh.y;
  float c2 = v2.x * wh.x + v2.y * wh.y;
  for (int m = 1; m < 64; m <<= 1) {
    d00 += __shfl_xor(d00, m, 64);
    c0 += __shfl_xor(c0, m, 64);
    c1 += __shfl_xor(c1, m, 64);
    c2 += __shfl_xor(c2, m, 64);
  }
  float b = bptr[0];
  float l0 = d00 + c0 + b, l1 = d00 + c1 + b, l2v = d00 + c2 + b;
  float mx = fmaxf(l0, fmaxf(l1, l2v));
  float a0 = expf(l0 - mx), a1 = expf(l1 - mx), a2 = expf(l2v - mx);
  float s = a0 + a1 + a2;
  a0 /= s; a1 /= s; a2 /= s;
  float2 o;
  o.x = a0 * v0.x + a1 * v1.x + a2 * v2.x;
  o.y = a0 * v0.y + a1 * v1.y + a2 * v2.y;
  *(float2*)(e0 + c) = o;
}

// gather batch rows: BPR accumulation + normalized P rows
__global__ void k_batch(const float* __restrict__ reps, const int* __restrict__ users,
                        const int* __restrict__ streamers, float* __restrict__ Pu,
                        float* __restrict__ Ps, float* __restrict__ accs) {
  int gid = blockIdx.x * blockDim.x + threadIdx.x;
  int wave = gid >> 6, lane = gid & 63;
  if (wave >= Bc) return;
  int u = users[wave];
  int s0 = streamers[wave * 2], s1 = streamers[wave * 2 + 1];
  const float2* ur = (const float2*)(reps + (size_t)u * D);
  const float2* ar = (const float2*)(reps + (size_t)(NUc + s0) * D);
  const float2* cr = (const float2*)(reps + (size_t)(NUc + s1) * D);
  float2 uv = ur[lane], av = ar[lane], cv = cr[lane];
  float p0 = uv.x * av.x + uv.y * av.y;
  float p1 = uv.x * cv.x + uv.y * cv.y;
  float un = uv.x * uv.x + uv.y * uv.y;
  float an = av.x * av.x + av.y * av.y;
  for (int m = 1; m < 64; m <<= 1) {
    p0 += __shfl_xor(p0, m, 64);
    p1 += __shfl_xor(p1, m, 64);
    un += __shfl_xor(un, m, 64);
    an += __shfl_xor(an, m, 64);
  }
  if (lane == 0) {
    float t = p0 - p1;
    float term = fmaxf(-t, 0.f) + log1pf(expf(-fabsf(t)));  // -log_sigmoid(t)
    atomicAdd(&accs[0], term);
  }
  float und = fmaxf(sqrtf(un), 1e-12f);
  float andv = fmaxf(sqrtf(an), 1e-12f);
  ((float2*)(Pu + (size_t)wave * D))[lane] = float2{uv.x / und, uv.y / und};
  ((float2*)(Ps + (size_t)wave * D))[lane] = float2{av.x / andv, av.y / andv};
}

// contrastive GEMM: S[b] += sum_j exp(5*dot(p_b,p_j))  (|logit|<=5, no max needed)
__global__ __launch_bounds__(256) void k_cgemm(const float* __restrict__ Pu,
                                               const float* __restrict__ Ps,
                                               float* __restrict__ Su,
                                               float* __restrict__ Ss) {
  const float* P = blockIdx.z ? Ps : Pu;
  float* S = blockIdx.z ? Ss : Su;
  __shared__ float A[32][132];
  __shared__ float BT[128][68];
  int tid = threadIdx.x;
  int tx = tid & 15, ty = tid >> 4;
  int brow0 = blockIdx.x * 32;
  int j0 = blockIdx.y * 512;
#pragma unroll
  for (int i = 0; i < 4; ++i) {
    int idx = tid + i * 256;
    int r = idx >> 5, c4 = idx & 31;
    float4 v = ((const float4*)(P + (size_t)(brow0 + r) * D))[c4];
    *(float4*)&A[r][c4 * 4] = v;
  }
  float s[2] = {0.f, 0.f};
  for (int jt = 0; jt < 8; ++jt) {
    __syncthreads();
#pragma unroll
    for (int i = 0; i < 8; ++i) {
      int idx = tid + i * 256;
      int r = idx >> 5, c4 = idx & 31;
      float4 v = ((const float4*)(P + (size_t)(j0 + jt * 64 + r) * D))[c4];
      BT[c4 * 4 + 0][r] = v.x;
      BT[c4 * 4 + 1][r] = v.y;
      BT[c4 * 4 + 2][r] = v.z;
      BT[c4 * 4 + 3][r] = v.w;
    }
    __syncthreads();
    float acc[2][4] = {};
    for (int k = 0; k < 128; k += 4) {
      float4 a0 = *(const float4*)&A[ty * 2 + 0][k];
      float4 a1 = *(const float4*)&A[ty * 2 + 1][k];
      float4 b0 = *(const float4*)&BT[k + 0][tx * 4];
      float4 b1 = *(const float4*)&BT[k + 1][tx * 4];
      float4 b2 = *(const float4*)&BT[k + 2][tx * 4];
      float4 b3 = *(const float4*)&BT[k + 3][tx * 4];
      acc[0][0] = fmaf(a0.x, b0.x, acc[0][0]); acc[0][1] = fmaf(a0.x, b0.y, acc[0][1]);
      acc[0][2] = fmaf(a0.x, b0.z, acc[0][2]); acc[0][3] = fmaf(a0.x, b0.w, acc[0][3]);
      acc[1][0] = fmaf(a1.x, b0.x, acc[1][0]); acc[1][1] = fmaf(a1.x, b0.y, acc[1][1]);
      acc[1][2] = fmaf(a1.x, b0.z, acc[1][2]); acc[1][3] = fmaf(a1.x, b0.w, acc[1][3]);
      acc[0][0] = fmaf(a0.y, b1.x, acc[0][0]); acc[0][1] = fmaf(a0.y, b1.y, acc[0][1]);
      acc[0][2] = fmaf(a0.y, b1.z, acc[0][2]); acc[0][3] = fmaf(a0.y, b1.w, acc[0][3]);
      acc[1][0] = fmaf(a1.y, b1.x, acc[1][0]); acc[1][1] = fmaf(a1.y, b1.y, acc[1][1]);
      acc[1][2] = fmaf(a1.y, b1.z, acc[1][2]); acc[1][3] = fmaf(a1.y, b1.w, acc[1][3]);
      acc[0][0] = fmaf(a0.z, b2.x, acc[0][0]); acc[0][1] = fmaf(a0.z, b2.y, acc[0][1]);
      acc[0][2] = fmaf(a0.z, b2.z, acc[0][2]); acc[0][3] = fmaf(a0.z, b2.w, acc[0][3]);
      acc[1][0] = fmaf(a1.z, b2.x, acc[1][0]); acc[1][1] = fmaf(a1.z, b2.y, acc[1][1]);
      acc[1][2] = fmaf(a1.z, b2.z, acc[1][2]); acc[1][3] = fmaf(a1.z, b2.w, acc[1][3]);
      acc[0][0] = fmaf(a0.w, b3.x, acc[0][0]); acc[0][1] = fmaf(a0.w, b3.y, acc[0][1]);
      acc[0][2] = fmaf(a0.w, b3.z, acc[0][2]); acc[0][3] = fmaf(a0.w, b3.w, acc[0][3]);
      acc[1][0] = fmaf(a1.w, b3.x, acc[1][0]); acc[1][1] = fmaf(a1.w, b3.y, acc[1][1]);
      acc[1][2] = fmaf(a1.w, b3.z, acc[1][2]); acc[1][3] = fmaf(a1.w, b3.w, acc[1][3]);
    }
#pragma unroll
    for (int i = 0; i < 2; ++i)
#pragma unroll
      for (int jj = 0; jj < 4; ++jj) s[i] += __expf(5.0f * acc[i][jj]);
  }
#pragma unroll
  for (int i = 0; i < 2; ++i) {
    for (int off = 1; off < 16; off <<= 1) s[i] += __shfl_xor(s[i], off, 64);
    if (tx == 0) atomicAdd(&S[brow0 + ty * 2 + i], s[i]);
  }
}

// finish: acc += log(S[b]) - 5*|p_b|^2
__global__ void k_cfinal(const float* __restrict__ Pu, const float* __restrict__ Ps,
                         const float* __restrict__ Su, const float* __restrict__ Ss,
                         float* __restrict__ accs) {
  int gid = blockIdx.x * blockDim.x + threadIdx.x;
  int wave = gid >> 6, lane = gid & 63;
  if (wave >= 2 * Bc) return;
  int loss = wave >> 11, b = wave & (Bc - 1);
  const float* P = loss ? Ps : Pu;
  const float* S = loss ? Ss : Su;
  float2 p = ((const float2*)(P + (size_t)b * D))[lane];
  float pos = p.x * p.x + p.y * p.y;
  for (int m = 1; m < 64; m <<= 1) pos += __shfl_xor(pos, m, 64);
  if (lane == 0) atomicAdd(&accs[1 + loss], logf(S[b]) - 5.0f * pos);
}

__global__ void k_final(const float* __restrict__ accs, float* __restrict__ out) {
  if (threadIdx.x == 0 && blockIdx.x == 0) {
    out[0] = accs[0] / (float)Bc;
    out[1] = 0.5f * (accs[1] + accs[2]) / (float)Bc;
  }
}

// ---------------- launch ----------------
extern "C" void kernel_launch(void* const* d_in, const int* in_sizes, int n_in,
                              void* d_out, int out_size, void* d_ws, size_t ws_size,
                              hipStream_t stream) {
  const float* usersF = (const float*)d_in[0];
  const float* streamersF = (const float*)d_in[1];
  const float* videosF = (const float*)d_in[2];
  const float* linW = (const float*)d_in[3];
  const float* linB = (const float*)d_in[4];
  const int* us_row = (const int*)d_in[5];
  const int* us_col = (const int*)d_in[6];
  const float* us_val = (const float*)d_in[7];
  const int* uv_row = (const int*)d_in[8];
  const int* uv_col = (const int*)d_in[9];
  const float* uv_val = (const float*)d_in[10];
  const int* sv_row = (const int*)d_in[11];
  const int* sv_col = (const int*)d_in[12];
  const float* sv_val = (const float*)d_in[13];
  const int* uva_row = (const int*)d_in[14];
  const int* uva_col = (const int*)d_in[15];
  const float* uva_val = (const float*)d_in[16];
  const int* sva_row = (const int*)d_in[17];
  const int* sva_col = (const int*)d_in[18];
  const float* sva_val = (const float*)d_in[19];
  const int* users = (const int*)d_in[20];
  const int* streamers = (const int*)d_in[21];
  const int nnz_us = in_sizes[5], nnz_uv = in_sizes[8], nnz_sv = in_sizes[11];
  const int nnz_uva = in_sizes[14], nnz_sva = in_sizes[17];
  float* out = (float*)d_out;

  float* ws = (float*)d_ws;
  size_t o = 0;
  float* UVm = ws + o; o += (size_t)(NUc + NVc) * D;   // 80000 rows f32
  float* SVm = ws + o; o += (size_t)(NSc + NVc) * D;   // 40000 rows f32
  float* USm = ws + o; o += (size_t)(NUc + NSc) * D;   // 60000 rows f32
  float* UVs = ws + o; o += (size_t)NSc * D;
  float* SVu = ws + o; o += (size_t)NUc * D;
  // fp16 gather buffers (allocated in float units, used as _Float16)
  _Float16* Fh = (_Float16*)(ws + o); o += (size_t)(NUc + NVc) * D / 2;
  _Float16* Th = (_Float16*)(ws + o); o += (size_t)(NUc + NVc) * D / 2;
  _Float16* Mh = (_Float16*)(ws + o); o += (size_t)(NUc + NVc) * D / 2;
  // loss scratch (f32)
  float* Pu = ws + o; o += (size_t)Bc * D;
  float* Ps = ws + o; o += (size_t)Bc * D;
  float* accs = ws + o; o += 16 + 2 * Bc;
  float* Su = accs + 16;
  float* Ss = Su + Bc;
  // CSR scratch regions aliased into dead f32 feature space:
  int* regA = (int*)UVm;                         // dead until UV prop's concat
  int* regB = (int*)SVm;                         // dead until SV prop's concat
  int* regC = (int*)(UVm + (size_t)NUc * D);     // UVm video half, dead after sva agg

  // key derivation (JAX threefry, partitionable fold-in split)
  uint32_t kus[2], kuv[2], ksv[2], kauv[2], kasv[2];
  threefry(0u, 42u, 0u, 0u, kus[0], kus[1]);
  threefry(0u, 42u, 0u, 1u, kuv[0], kuv[1]);
  threefry(0u, 42u, 0u, 2u, ksv[0], ksv[1]);
  threefry(0u, 42u, 0u, 3u, kauv[0], kauv[1]);
  threefry(0u, 42u, 0u, 4u, kasv[0], kasv[1]);
  uint32_t kusL[2][2], kuvL[2][2], ksvL[2][2];
  for (uint32_t i = 0; i < 2; ++i) {
    threefry(kus[0], kus[1], 0u, i, kusL[i][0], kusL[i][1]);
    threefry(kuv[0], kuv[1], 0u, i, kuvL[i][0], kuvL[i][1]);
    threefry(ksv[0], ksv[1], 0u, i, ksvL[i][0], ksvL[i][1]);
  }

  // CSR region layout: [cv: 2*nnz ints] [rp: n+1] [cursor: n] [aux: <=128]
  auto build_csr = [&](int* region, const int* grow, const int* gcol, const float* gval,
                       int nnz, int n, int2*& cv, int*& rp) {
    cv = (int2*)region;
    rp = region + (size_t)2 * nnz;
    int* cur = rp + (n + 1);
    int* aux = cur + n;
    int nsc = n + 1;
    int nb = (nsc + 1023) / 1024;
    hipMemsetAsync(rp, 0, (size_t)nsc * sizeof(int), stream);
    k_hist<<<(unsigned)((nnz + 255) / 256), 256, 0, stream>>>(grow, nnz, rp);
    k_scan1<<<(unsigned)nb, 1024, 0, stream>>>(rp, nsc, aux);
    k_scan2<<<1, 64, 0, stream>>>(aux, nb);
    k_scan3<<<(unsigned)nb, 1024, 0, stream>>>(rp, nsc, aux);
    k_copy<<<(unsigned)((n + 255) / 256), 256, 0, stream>>>(rp, cur, n);
    k_scatter<<<(unsigned)((nnz + 255) / 256), 256, 0, stream>>>(grow, gcol, gval, nnz, cur, cv);
  };

  auto run_prop = [&](const float* a, int na, const float* b, int nb, int* region,
                      const int* grow, const int* gcol, const float* gval, int nnz,
                      float* acc, _Float16* meanh, const uint32_t (&kL)[2][2]) {
    int n = na + nb;
    int2* cv; int* rp;
    build_csr(region, grow, gcol, gval, nnz, n, cv, rp);
    size_t tot4 = (size_t)n * (D / 4);
    k_concat<<<(unsigned)((tot4 + 255) / 256), 256, 0, stream>>>(a, na, b, nb, Fh, acc);
    k_gprop<<<(unsigned)((n + 3) / 4), 256, 0, stream>>>(rp, cv, Fh, Th, acc, (_Float16*)nullptr,
                                                         n, 0.1f, 1.0f, kL[0][0], kL[0][1]);
    k_gprop<<<(unsigned)((n + 3) / 4), 256, 0, stream>>>(rp, cv, Th, Fh, acc, meanh,
                                                         n, 0.1f, 3.0f, kL[1][0], kL[1][1]);
  };

  auto run_agg = [&](int* region, const int* grow, const int* gcol, const float* gval, int nnz,
                     const _Float16* hsrc, int n_out, float* dst, const uint32_t (&k)[2]) {
    int2* cv; int* rp;
    build_csr(region, grow, gcol, gval, nnz, n_out, cv, rp);
    k_gagg<<<(unsigned)((n_out + 3) / 4), 256, 0, stream>>>(rp, cv, hsrc, dst, n_out, 0.1f,
                                                            k[0], k[1]);
  };

  // US propagate first (CSR in UVm space; no mean_h needed)
  run_prop(usersF, NUc, streamersF, NSc, regA, us_row, us_col, us_val, nnz_us, USm,
           (_Float16*)nullptr, kusL);
  // UV propagate (CSR in SVm space; Mh = fp16 mean) ; UV_s aggregate from Mh video half
  run_prop(usersF, NUc, videosF, NVc, regB, uv_row, uv_col, uv_val, nnz_uv, UVm, Mh, kuvL);
  run_agg(regB, sva_row, sva_col, sva_val, nnz_sva, Mh + (size_t)NUc * D, NSc, UVs, kasv);
  // SV propagate (CSR in UVm video half; rewrites Mh) ; SV_u aggregate from Mh video half
  run_prop(streamersF, NSc, videosF, NVc, regC, sv_row, sv_col, sv_val, nnz_sv, SVm, Mh, ksvL);
  run_agg(regC, uva_row, uva_col, uva_val, nnz_uva, Mh + (size_t)NSc * D, NUc, SVu, kauv);
  // MGA attention in-place into USm -> [users_rep ; streamers_rep]
  k_mga<<<(unsigned)((NUc + NSc + 3) / 4), 256, 0, stream>>>(USm, UVm, UVs, SVu, SVm, linW, linB);
  // losses
  hipMemsetAsync(accs, 0, (16 + 2 * Bc) * sizeof(float), stream);
  k_batch<<<(unsigned)((Bc + 3) / 4), 256, 0, stream>>>(USm, users, streamers, Pu, Ps, accs);
  k_cgemm<<<dim3(Bc / 32, 4, 2), 256, 0, stream>>>(Pu, Ps, Su, Ss);
  k_cfinal<<<(unsigned)((2 * Bc + 3) / 4), 256, 0, stream>>>(Pu, Ps, Su, Ss, accs);
  k_final<<<1, 64, 0, stream>>>(accs, out);
}

// Round 5
// 1037.304 us; speedup vs baseline: 11.4561x; 1.1733x over previous
//
#include <hip/hip_runtime.h>
#include <stdint.h>

#define D 128
constexpr int NUc = 50000, NSc = 10000, NVc = 30000, Bc = 2048;
constexpr int N_US = 60000, N_UV = 80000, N_SV = 40000, N_ALL = 90000;

typedef _Float16 h2v __attribute__((ext_vector_type(2)));
typedef _Float16 h4v __attribute__((ext_vector_type(4)));

// ---------------- Threefry-2x32 (JAX) ----------------
__host__ __device__ inline void threefry(uint32_t k0, uint32_t k1, uint32_t x0, uint32_t x1,
                                         uint32_t& o0, uint32_t& o1) {
  uint32_t ks2 = k0 ^ k1 ^ 0x1BD11BDAu;
  uint32_t v0 = x0 + k0, v1 = x1 + k1;
#define TFR(r) { v0 += v1; v1 = (v1 << (r)) | (v1 >> (32 - (r))); v1 ^= v0; }
  TFR(13) TFR(15) TFR(26) TFR(6)   v0 += k1;  v1 += ks2 + 1u;
  TFR(17) TFR(29) TFR(16) TFR(24)  v0 += ks2; v1 += k0 + 2u;
  TFR(13) TFR(15) TFR(26) TFR(6)   v0 += k0;  v1 += k1 + 3u;
  TFR(17) TFR(29) TFR(16) TFR(24)  v0 += k1;  v1 += ks2 + 4u;
  TFR(13) TFR(15) TFR(26) TFR(6)   v0 += ks2; v1 += k0 + 5u;
#undef TFR
  o0 = v0; o1 = v1;
}

__device__ __forceinline__ float unif01(uint32_t k0, uint32_t k1, uint32_t j) {
  uint32_t a, b;
  threefry(k0, k1, 0u, j, a, b);
  uint32_t bits = a ^ b;
  return __uint_as_float(0x3F800000u | (bits >> 9)) - 1.0f;
}

// ---------------- fused CSR build over 5 graphs ----------------
struct Bld {
  const int* rows[5]; const int* cols[5]; const float* vals[5];
  int* rp[5]; int* cur[5]; int* aux[5]; int2* cv[5];
  int eBase[6];    // cumulative edges
  int sBlkBase[6]; // cumulative scan blocks
  int nPlus1[5];   // scan length per graph
};

__global__ void k_hist5(Bld b) {
  int gid = blockIdx.x * blockDim.x + threadIdx.x;
  if (gid >= b.eBase[5]) return;
  int g = 0;
  while (gid >= b.eBase[g + 1]) ++g;
  int e = gid - b.eBase[g];
  atomicAdd(&b.rp[g][b.rows[g][e] + 1], 1);
}

__global__ __launch_bounds__(1024) void k_scan1f(Bld b) {
  __shared__ int wsum[16];
  int blk = blockIdx.x;
  int g = 0;
  while (blk >= b.sBlkBase[g + 1]) ++g;
  int lb = blk - b.sBlkBase[g];
  int n = b.nPlus1[g];
  int* data = b.rp[g];
  int tid = threadIdx.x, lane = tid & 63, w = tid >> 6;
  int i = lb * 1024 + tid;
  int x = (i < n) ? data[i] : 0;
  for (int off = 1; off < 64; off <<= 1) {
    int t = __shfl_up(x, off, 64);
    if (lane >= off) x += t;
  }
  if (lane == 63) wsum[w] = x;
  __syncthreads();
  if (w == 0 && lane < 16) {
    int s = wsum[lane];
    for (int off = 1; off < 16; off <<= 1) {
      int t = __shfl_up(s, off, 64);
      if (lane >= off) s += t;
    }
    wsum[lane] = s;
  }
  __syncthreads();
  int woff = (w > 0) ? wsum[w - 1] : 0;
  if (i < n) data[i] = x + woff;
  if (tid == 1023) b.aux[g][lb] = x + woff;
}

__global__ void k_scan2f(Bld b) {
  int g = blockIdx.x;
  int nb = b.sBlkBase[g + 1] - b.sBlkBase[g];
  int* aux = b.aux[g];
  int lane = threadIdx.x;  // 64 threads
  int carry = 0;
  for (int base = 0; base < nb; base += 64) {
    int i = base + lane;
    int v = (i < nb) ? aux[i] : 0;
    for (int off = 1; off < 64; off <<= 1) {
      int t = __shfl_up(v, off, 64);
      if (lane >= off) v += t;
    }
    if (i < nb) aux[i] = v + carry;
    carry += __shfl(v, 63, 64);
  }
}

// add block offsets + init cursor = row starts
__global__ __launch_bounds__(1024) void k_scan3f(Bld b) {
  int blk = blockIdx.x;
  int g = 0;
  while (blk >= b.sBlkBase[g + 1]) ++g;
  int lb = blk - b.sBlkBase[g];
  int i = lb * 1024 + threadIdx.x;
  int n1 = b.nPlus1[g];
  if (i >= n1) return;
  int v = b.rp[g][i];
  if (lb > 0) { v += b.aux[g][lb - 1]; b.rp[g][i] = v; }
  if (i < n1 - 1) b.cur[g][i] = v;
}

__global__ void k_scat5(Bld b) {
  int gid = blockIdx.x * blockDim.x + threadIdx.x;
  if (gid >= b.eBase[5]) return;
  int g = 0;
  while (gid >= b.eBase[g + 1]) ++g;
  int e = gid - b.eBase[g];
  int pos = atomicAdd(&b.cur[g][b.rows[g][e]], 1);
  b.cv[g][pos] = make_int2(b.cols[g][e], __float_as_int(b.vals[g][e]));
}

// ---------------- layer-0 shared fp16 table [users|streamers|videos] ----------------
__global__ void k_l0(const float* __restrict__ u, const float* __restrict__ s,
                     const float* __restrict__ v, _Float16* __restrict__ L0) {
  int gid = blockIdx.x * blockDim.x + threadIdx.x;  // h4v units
  const int tot = N_ALL * (D / 4);
  if (gid >= tot) return;
  int r = gid >> 5, c4 = gid & 31;
  const float* src = (r < NUc) ? u + (size_t)r * D
                   : (r < NUc + NSc) ? s + (size_t)(r - NUc) * D
                                     : v + (size_t)(r - NUc - NSc) * D;
  float4 x = ((const float4*)src)[c4];
  ((h4v*)L0)[gid] = h4v{(_Float16)x.x, (_Float16)x.y, (_Float16)x.z, (_Float16)x.w};
}

// ---------------- gather core (wave per row, fp16 src, unroll 4) ----------------
__device__ __forceinline__ void gather_row(const int* __restrict__ rp,
                                           const int2* __restrict__ cv,
                                           const char* __restrict__ spc, int rl, uint32_t lo,
                                           int thr, int addLo, int addHi,
                                           float& fx, float& fy) {
  int s = rp[rl], e = rp[rl + 1];
  int k = s;
  for (; k + 3 < e; k += 4) {
    int2 q0 = cv[k], q1 = cv[k + 1], q2 = cv[k + 2], q3 = cv[k + 3];
    uint32_t c0 = (uint32_t)(q0.x + (q0.x >= thr ? addHi : addLo));
    uint32_t c1 = (uint32_t)(q1.x + (q1.x >= thr ? addHi : addLo));
    uint32_t c2 = (uint32_t)(q2.x + (q2.x >= thr ? addHi : addLo));
    uint32_t c3 = (uint32_t)(q3.x + (q3.x >= thr ? addHi : addLo));
    h2v x0 = *(const h2v*)(spc + (c0 << 8) + lo);
    h2v x1 = *(const h2v*)(spc + (c1 << 8) + lo);
    h2v x2 = *(const h2v*)(spc + (c2 << 8) + lo);
    h2v x3 = *(const h2v*)(spc + (c3 << 8) + lo);
    float v0 = __int_as_float(q0.y), v1 = __int_as_float(q1.y);
    float v2 = __int_as_float(q2.y), v3 = __int_as_float(q3.y);
    fx = fmaf(v0, (float)x0.x, fx); fy = fmaf(v0, (float)x0.y, fy);
    fx = fmaf(v1, (float)x1.x, fx); fy = fmaf(v1, (float)x1.y, fy);
    fx = fmaf(v2, (float)x2.x, fx); fy = fmaf(v2, (float)x2.y, fy);
    fx = fmaf(v3, (float)x3.x, fx); fy = fmaf(v3, (float)x3.y, fy);
  }
  for (; k < e; ++k) {
    int2 q = cv[k];
    uint32_t c = (uint32_t)(q.x + (q.x >= thr ? addHi : addLo));
    h2v x = *(const h2v*)(spc + (c << 8) + lo);
    float v = __int_as_float(q.y);
    fx = fmaf(v, (float)x.x, fx); fy = fmaf(v, (float)x.y, fy);
  }
}

// ---------------- fused propagate layer over 3 graphs ----------------
struct GP {
  const int* rp[3]; const int2* cv[3];
  const _Float16* src[3];    // gather source
  const _Float16* accIn[3];  // own-row accumulator input
  _Float16* accOut[3];
  _Float16* dst[3];          // null on layer 2
  uint32_t k0[3], k1[3];
  int thr[3], addLo[3], addHi[3];
  int rBase[4];
  float div;
};

__global__ void k_gprop3(GP p) {
  int gid = blockIdx.x * blockDim.x + threadIdx.x;
  int r = gid >> 6, lane = gid & 63;
  if (r >= p.rBase[3]) return;
  int g = 0;
  while (r >= p.rBase[g + 1]) ++g;
  int rl = r - p.rBase[g];
  uint32_t lo = (uint32_t)lane << 2;
  float fx = 0.f, fy = 0.f;
  gather_row(p.rp[g], p.cv[g], (const char*)p.src[g], rl, lo,
             p.thr[g], p.addLo[g], p.addHi[g], fx, fy);
  uint32_t j0 = (uint32_t)rl * D + (uint32_t)lane * 2;
  float u0 = unif01(p.k0[g], p.k1[g], j0);
  float u1 = unif01(p.k0[g], p.k1[g], j0 + 1u);
  float s2 = u0 * u0 + u1 * u1;
  for (int m = 1; m < 64; m <<= 1) s2 += __shfl_xor(s2, m, 64);
  float nn = fmaxf(sqrtf(s2), 1e-12f);
  float sg0 = (fx > 0.f) ? 1.f : ((fx < 0.f) ? -1.f : 0.f);
  float sg1 = (fy > 0.f) ? 1.f : ((fy < 0.f) ? -1.f : 0.f);
  float nf0 = fx + sg0 * (u0 / nn) * 0.1f;
  float nf1 = fy + sg1 * (u1 / nn) * 0.1f;
  float fs = nf0 * nf0 + nf1 * nf1;
  for (int m = 1; m < 64; m <<= 1) fs += __shfl_xor(fs, m, 64);
  float fn = fmaxf(sqrtf(fs), 1e-12f);
  int gr = rl + (rl >= p.thr[g] ? p.addHi[g] : p.addLo[g]);  // row remap for accIn space
  h2v ai = ((const h2v*)p.accIn[g])[(size_t)gr * (D / 2) + lane];
  float ax = ((float)ai.x + nf0 / fn) / p.div;
  float ay = ((float)ai.y + nf1 / fn) / p.div;
  ((h2v*)p.accOut[g])[(size_t)rl * (D / 2) + lane] = h2v{(_Float16)ax, (_Float16)ay};
  if (p.dst[g])
    ((h2v*)p.dst[g])[(size_t)rl * (D / 2) + lane] = h2v{(_Float16)nf0, (_Float16)nf1};
}

// ---------------- fused aggregate over 2 graphs ----------------
struct GA {
  const int* rp[2]; const int2* cv[2];
  const _Float16* src[2]; _Float16* dst[2];
  uint32_t k0[2], k1[2];
  int rBase[3];
};

__global__ void k_gagg2(GA a) {
  int gid = blockIdx.x * blockDim.x + threadIdx.x;
  int r = gid >> 6, lane = gid & 63;
  if (r >= a.rBase[2]) return;
  int g = (r >= a.rBase[1]) ? 1 : 0;
  int rl = r - a.rBase[g];
  uint32_t lo = (uint32_t)lane << 2;
  float fx = 0.f, fy = 0.f;
  gather_row(a.rp[g], a.cv[g], (const char*)a.src[g], rl, lo, 0x7fffffff, 0, 0, fx, fy);
  uint32_t j0 = (uint32_t)rl * D + (uint32_t)lane * 2;
  float u0 = unif01(a.k0[g], a.k1[g], j0);
  float u1 = unif01(a.k0[g], a.k1[g], j0 + 1u);
  float s2 = u0 * u0 + u1 * u1;
  for (int m = 1; m < 64; m <<= 1) s2 += __shfl_xor(s2, m, 64);
  float nn = fmaxf(sqrtf(s2), 1e-12f);
  float sg0 = (fx > 0.f) ? 1.f : ((fx < 0.f) ? -1.f : 0.f);
  float sg1 = (fy > 0.f) ? 1.f : ((fy < 0.f) ? -1.f : 0.f);
  ((h2v*)a.dst[g])[(size_t)rl * (D / 2) + lane] =
      h2v{(_Float16)(fx + sg0 * (u0 / nn) * 0.1f), (_Float16)(fy + sg1 * (u1 / nn) * 0.1f)};
}

// ---------------- MGA attention (fp16 in/out, in-place into e0buf) ----------------
__global__ void k_mga(_Float16* __restrict__ e0buf, const _Float16* __restrict__ UVa,
                      const _Float16* __restrict__ UVs, const _Float16* __restrict__ SVu,
                      const _Float16* __restrict__ SVa, const float* __restrict__ w,
                      const float* __restrict__ bptr) {
  int gid = blockIdx.x * blockDim.x + threadIdx.x;
  int wave = gid >> 6, lane = gid & 63;
  int n = NUc + NSc;
  if (wave >= n) return;
  const _Float16* e1 = (wave < NUc) ? UVa + (size_t)wave * D : UVs + (size_t)(wave - NUc) * D;
  const _Float16* e2 = (wave < NUc) ? SVu + (size_t)wave * D : SVa + (size_t)(wave - NUc) * D;
  _Float16* e0 = e0buf + (size_t)wave * D;
  int c = lane * 2;
  h2v h0 = *(const h2v*)(e0 + c), h1 = *(const h2v*)(e1 + c), h2_ = *(const h2v*)(e2 + c);
  float2 v0 = {(float)h0.x, (float)h0.y};
  float2 v1 = {(float)h1.x, (float)h1.y};
  float2 v2 = {(float)h2_.x, (float)h2_.y};
  float2 wl = *(const float2*)(w + c);
  float2 wh = *(const float2*)(w + D + c);
  float d00 = v0.x * wl.x + v0.y * wl.y;
  float c0 = v0.x * wh.x + v0.y * wh.y;
  float c1 = v1.x * wh.x + v1.y * wh.y;
  float c2 = v2.x * wh.x + v2.y * wh.y;
  for (int m = 1; m < 64; m <<= 1) {
    d00 += __shfl_xor(d00, m, 64);
    c0 += __shfl_xor(c0, m, 64);
    c1 += __shfl_xor(c1, m, 64);
    c2 += __shfl_xor(c2, m, 64);
  }
  float b = bptr[0];
  float l0 = d00 + c0 + b, l1 = d00 + c1 + b, l2v = d00 + c2 + b;
  float mx = fmaxf(l0, fmaxf(l1, l2v));
  float a0 = expf(l0 - mx), a1 = expf(l1 - mx), a2 = expf(l2v - mx);
  float s = a0 + a1 + a2;
  a0 /= s; a1 /= s; a2 /= s;
  float ox = a0 * v0.x + a1 * v1.x + a2 * v2.x;
  float oy = a0 * v0.y + a1 * v1.y + a2 * v2.y;
  *(h2v*)(e0 + c) = h2v{(_Float16)ox, (_Float16)oy};
}

// ---------------- batch gather: BPR + normalized P rows ----------------
__global__ void k_batch(const _Float16* __restrict__ reps, const int* __restrict__ users,
                        const int* __restrict__ streamers, float* __restrict__ Pu,
                        float* __restrict__ Ps, float* __restrict__ accs) {
  int gid = blockIdx.x * blockDim.x + threadIdx.x;
  int wave = gid >> 6, lane = gid & 63;
  if (wave >= Bc) return;
  int u = users[wave];
  int s0 = streamers[wave * 2], s1 = streamers[wave * 2 + 1];
  h2v uh = ((const h2v*)(reps + (size_t)u * D))[lane];
  h2v ah = ((const h2v*)(reps + (size_t)(NUc + s0) * D))[lane];
  h2v ch = ((const h2v*)(reps + (size_t)(NUc + s1) * D))[lane];
  float2 uv = {(float)uh.x, (float)uh.y};
  float2 av = {(float)ah.x, (float)ah.y};
  float2 cv = {(float)ch.x, (float)ch.y};
  float p0 = uv.x * av.x + uv.y * av.y;
  float p1 = uv.x * cv.x + uv.y * cv.y;
  float un = uv.x * uv.x + uv.y * uv.y;
  float an = av.x * av.x + av.y * av.y;
  for (int m = 1; m < 64; m <<= 1) {
    p0 += __shfl_xor(p0, m, 64);
    p1 += __shfl_xor(p1, m, 64);
    un += __shfl_xor(un, m, 64);
    an += __shfl_xor(an, m, 64);
  }
  if (lane == 0) {
    float t = p0 - p1;
    float term = fmaxf(-t, 0.f) + log1pf(expf(-fabsf(t)));  // -log_sigmoid(t)
    atomicAdd(&accs[0], term);
  }
  float und = fmaxf(sqrtf(un), 1e-12f);
  float andv = fmaxf(sqrtf(an), 1e-12f);
  ((float2*)(Pu + (size_t)wave * D))[lane] = float2{uv.x / und, uv.y / und};
  ((float2*)(Ps + (size_t)wave * D))[lane] = float2{av.x / andv, av.y / andv};
}

// ---------------- contrastive GEMM: S[b] += sum_j exp(5*dot) ----------------
__global__ __launch_bounds__(256) void k_cgemm(const float* __restrict__ Pu,
                                               const float* __restrict__ Ps,
                                               float* __restrict__ Su,
                                               float* __restrict__ Ss) {
  const float* P = blockIdx.z ? Ps : Pu;
  float* S = blockIdx.z ? Ss : Su;
  __shared__ float A[32][132];
  __shared__ float BT[128][68];
  int tid = threadIdx.x;
  int tx = tid & 15, ty = tid >> 4;
  int brow0 = blockIdx.x * 32;
  int j0 = blockIdx.y * 512;
#pragma unroll
  for (int i = 0; i < 4; ++i) {
    int idx = tid + i * 256;
    int r = idx >> 5, c4 = idx & 31;
    float4 v = ((const float4*)(P + (size_t)(brow0 + r) * D))[c4];
    *(float4*)&A[r][c4 * 4] = v;
  }
  float s[2] = {0.f, 0.f};
  for (int jt = 0; jt < 8; ++jt) {
    __syncthreads();
#pragma unroll
    for (int i = 0; i < 8; ++i) {
      int idx = tid + i * 256;
      int r = idx >> 5, c4 = idx & 31;
      float4 v = ((const float4*)(P + (size_t)(j0 + jt * 64 + r) * D))[c4];
      BT[c4 * 4 + 0][r] = v.x;
      BT[c4 * 4 + 1][r] = v.y;
      BT[c4 * 4 + 2][r] = v.z;
      BT[c4 * 4 + 3][r] = v.w;
    }
    __syncthreads();
    float acc[2][4] = {};
    for (int k = 0; k < 128; k += 4) {
      float4 a0 = *(const float4*)&A[ty * 2 + 0][k];
      float4 a1 = *(const float4*)&A[ty * 2 + 1][k];
      float4 b0 = *(const float4*)&BT[k + 0][tx * 4];
      float4 b1 = *(const float4*)&BT[k + 1][tx * 4];
      float4 b2 = *(const float4*)&BT[k + 2][tx * 4];
      float4 b3 = *(const float4*)&BT[k + 3][tx * 4];
      acc[0][0] = fmaf(a0.x, b0.x, acc[0][0]); acc[0][1] = fmaf(a0.x, b0.y, acc[0][1]);
      acc[0][2] = fmaf(a0.x, b0.z, acc[0][2]); acc[0][3] = fmaf(a0.x, b0.w, acc[0][3]);
      acc[1][0] = fmaf(a1.x, b0.x, acc[1][0]); acc[1][1] = fmaf(a1.x, b0.y, acc[1][1]);
      acc[1][2] = fmaf(a1.x, b0.z, acc[1][2]); acc[1][3] = fmaf(a1.x, b0.w, acc[1][3]);
      acc[0][0] = fmaf(a0.y, b1.x, acc[0][0]); acc[0][1] = fmaf(a0.y, b1.y, acc[0][1]);
      acc[0][2] = fmaf(a0.y, b1.z, acc[0][2]); acc[0][3] = fmaf(a0.y, b1.w, acc[0][3]);
      acc[1][0] = fmaf(a1.y, b1.x, acc[1][0]); acc[1][1] = fmaf(a1.y, b1.y, acc[1][1]);
      acc[1][2] = fmaf(a1.y, b1.z, acc[1][2]); acc[1][3] = fmaf(a1.y, b1.w, acc[1][3]);
      acc[0][0] = fmaf(a0.z, b2.x, acc[0][0]); acc[0][1] = fmaf(a0.z, b2.y, acc[0][1]);
      acc[0][2] = fmaf(a0.z, b2.z, acc[0][2]); acc[0][3] = fmaf(a0.z, b2.w, acc[0][3]);
      acc[1][0] = fmaf(a1.z, b2.x, acc[1][0]); acc[1][1] = fmaf(a1.z, b2.y, acc[1][1]);
      acc[1][2] = fmaf(a1.z, b2.z, acc[1][2]); acc[1][3] = fmaf(a1.z, b2.w, acc[1][3]);
      acc[0][0] = fmaf(a0.w, b3.x, acc[0][0]); acc[0][1] = fmaf(a0.w, b3.y, acc[0][1]);
      acc[0][2] = fmaf(a0.w, b3.z, acc[0][2]); acc[0][3] = fmaf(a0.w, b3.w, acc[0][3]);
      acc[1][0] = fmaf(a1.w, b3.x, acc[1][0]); acc[1][1] = fmaf(a1.w, b3.y, acc[1][1]);
      acc[1][2] = fmaf(a1.w, b3.z, acc[1][2]); acc[1][3] = fmaf(a1.w, b3.w, acc[1][3]);
    }
#pragma unroll
    for (int i = 0; i < 2; ++i)
#pragma unroll
      for (int jj = 0; jj < 4; ++jj) s[i] += __expf(5.0f * acc[i][jj]);
  }
#pragma unroll
  for (int i = 0; i < 2; ++i) {
    for (int off = 1; off < 16; off <<= 1) s[i] += __shfl_xor(s[i], off, 64);
    if (tx == 0) atomicAdd(&S[brow0 + ty * 2 + i], s[i]);
  }
}

__global__ void k_cfinal(const float* __restrict__ Pu, const float* __restrict__ Ps,
                         const float* __restrict__ Su, const float* __restrict__ Ss,
                         float* __restrict__ accs) {
  int gid = blockIdx.x * blockDim.x + threadIdx.x;
  int wave = gid >> 6, lane = gid & 63;
  if (wave >= 2 * Bc) return;
  int loss = wave >> 11, b = wave & (Bc - 1);
  const float* P = loss ? Ps : Pu;
  const float* S = loss ? Ss : Su;
  float2 p = ((const float2*)(P + (size_t)b * D))[lane];
  float pos = p.x * p.x + p.y * p.y;
  for (int m = 1; m < 64; m <<= 1) pos += __shfl_xor(pos, m, 64);
  if (lane == 0) atomicAdd(&accs[1 + loss], logf(S[b]) - 5.0f * pos);
}

__global__ void k_final(const float* __restrict__ accs, float* __restrict__ out) {
  if (threadIdx.x == 0 && blockIdx.x == 0) {
    out[0] = accs[0] / (float)Bc;
    out[1] = 0.5f * (accs[1] + accs[2]) / (float)Bc;
  }
}

// ---------------- launch ----------------
extern "C" void kernel_launch(void* const* d_in, const int* in_sizes, int n_in,
                              void* d_out, int out_size, void* d_ws, size_t ws_size,
                              hipStream_t stream) {
  const float* usersF = (const float*)d_in[0];
  const float* streamersF = (const float*)d_in[1];
  const float* videosF = (const float*)d_in[2];
  const float* linW = (const float*)d_in[3];
  const float* linB = (const float*)d_in[4];
  const int* grows[5] = {(const int*)d_in[5], (const int*)d_in[8], (const int*)d_in[11],
                         (const int*)d_in[14], (const int*)d_in[17]};
  const int* gcols[5] = {(const int*)d_in[6], (const int*)d_in[9], (const int*)d_in[12],
                         (const int*)d_in[15], (const int*)d_in[18]};
  const float* gvals[5] = {(const float*)d_in[7], (const float*)d_in[10], (const float*)d_in[13],
                           (const float*)d_in[16], (const float*)d_in[19]};
  const int* users = (const int*)d_in[20];
  const int* streamers = (const int*)d_in[21];
  int nnz[5] = {in_sizes[5], in_sizes[8], in_sizes[11], in_sizes[14], in_sizes[17]};
  int gn[5] = {N_US, N_UV, N_SV, NUc, NSc};  // us, uv, sv, uva, sva
  float* out = (float*)d_out;

  // ---------- workspace ----------
  char* pb = (char*)d_ws;
  auto allocH = [&](size_t nh) { _Float16* p = (_Float16*)pb; pb += nh * 2; return p; };
  _Float16* L0 = allocH((size_t)N_ALL * D);
  _Float16* Th[3] = {allocH((size_t)N_US * D), allocH((size_t)N_UV * D), allocH((size_t)N_SV * D)};
  _Float16* Ac[3] = {allocH((size_t)N_US * D), allocH((size_t)N_UV * D), allocH((size_t)N_SV * D)};
  _Float16* UVsH = allocH((size_t)NSc * D);
  _Float16* SVuH = allocH((size_t)NUc * D);
  pb = (char*)(((uintptr_t)pb + 15) & ~(uintptr_t)15);
  float* Pu = (float*)pb; pb += (size_t)Bc * D * 4;
  float* Ps = (float*)pb; pb += (size_t)Bc * D * 4;
  float* accs = (float*)pb; pb += 16 * 4;
  float* Su = (float*)pb; pb += Bc * 4;
  float* Ss = (float*)pb; pb += Bc * 4;
  int totE = nnz[0] + nnz[1] + nnz[2] + nnz[3] + nnz[4];
  int2* cvAll = (int2*)pb; pb += (size_t)totE * 8;
  int* rpAll = (int*)pb;
  int totRP = 0;
  for (int g = 0; g < 5; ++g) totRP += gn[g] + 1;
  pb += (size_t)totRP * 4;
  int* curAll = (int*)pb; pb += (size_t)(totRP - 5) * 4;
  int* auxAll = (int*)pb; pb += 5 * 128 * 4;

  // ---------- CSR build descriptor ----------
  Bld b;
  {
    int eA = 0, sA = 0, rpO = 0, curO = 0, cvO = 0;
    for (int g = 0; g < 5; ++g) {
      b.rows[g] = grows[g]; b.cols[g] = gcols[g]; b.vals[g] = gvals[g];
      b.eBase[g] = eA; eA += nnz[g];
      int n1 = gn[g] + 1;
      b.nPlus1[g] = n1;
      b.sBlkBase[g] = sA; sA += (n1 + 1023) / 1024;
      b.rp[g] = rpAll + rpO; rpO += n1;
      b.cur[g] = curAll + curO; curO += gn[g];
      b.aux[g] = auxAll + g * 128;
      b.cv[g] = cvAll + cvO; cvO += nnz[g];
    }
    b.eBase[5] = eA;
    b.sBlkBase[5] = sA;
  }
  int totBlk = b.sBlkBase[5];

  // ---------- keys (JAX threefry, partitionable fold-in split) ----------
  uint32_t kus[2], kuv[2], ksv[2], kauv[2], kasv[2];
  threefry(0u, 42u, 0u, 0u, kus[0], kus[1]);
  threefry(0u, 42u, 0u, 1u, kuv[0], kuv[1]);
  threefry(0u, 42u, 0u, 2u, ksv[0], ksv[1]);
  threefry(0u, 42u, 0u, 3u, kauv[0], kauv[1]);
  threefry(0u, 42u, 0u, 4u, kasv[0], kasv[1]);
  uint32_t kusL[2][2], kuvL[2][2], ksvL[2][2];
  for (uint32_t i = 0; i < 2; ++i) {
    threefry(kus[0], kus[1], 0u, i, kusL[i][0], kusL[i][1]);
    threefry(kuv[0], kuv[1], 0u, i, kuvL[i][0], kuvL[i][1]);
    threefry(ksv[0], ksv[1], 0u, i, ksvL[i][0], ksvL[i][1]);
  }

  // ---------- CSR build (6 launches incl. memset) ----------
  hipMemsetAsync(rpAll, 0, (size_t)totRP * sizeof(int), stream);
  k_hist5<<<(unsigned)((totE + 255) / 256), 256, 0, stream>>>(b);
  k_scan1f<<<(unsigned)totBlk, 1024, 0, stream>>>(b);
  k_scan2f<<<5, 64, 0, stream>>>(b);
  k_scan3f<<<(unsigned)totBlk, 1024, 0, stream>>>(b);
  k_scat5<<<(unsigned)((totE + 255) / 256), 256, 0, stream>>>(b);

  // ---------- layer-0 shared table ----------
  k_l0<<<(unsigned)((N_ALL * (D / 4) + 255) / 256), 256, 0, stream>>>(usersF, streamersF,
                                                                      videosF, L0);

  // ---------- propagate layers (fused over us/uv/sv) ----------
  // col/row remap local->global L0 space: us identity; uv: c<NU? c : c+NS; sv: c+NU
  GP p1, p2;
  const uint32_t* kL1[3] = {kusL[0], kuvL[0], ksvL[0]};
  const uint32_t* kL2[3] = {kusL[1], kuvL[1], ksvL[1]};
  int rB[4] = {0, N_US, N_US + N_UV, N_US + N_UV + N_SV};
  int thr1[3] = {0x7fffffff, NUc, 0};
  int aLo1[3] = {0, 0, NUc};
  int aHi1[3] = {0, NSc, NUc};
  for (int g = 0; g < 3; ++g) {
    p1.rp[g] = b.rp[g]; p1.cv[g] = b.cv[g];
    p1.src[g] = L0; p1.accIn[g] = L0; p1.accOut[g] = Ac[g]; p1.dst[g] = Th[g];
    p1.k0[g] = kL1[g][0]; p1.k1[g] = kL1[g][1];
    p1.thr[g] = thr1[g]; p1.addLo[g] = aLo1[g]; p1.addHi[g] = aHi1[g];
    p1.rBase[g] = rB[g];
    p2.rp[g] = b.rp[g]; p2.cv[g] = b.cv[g];
    p2.src[g] = Th[g]; p2.accIn[g] = Ac[g]; p2.accOut[g] = Ac[g]; p2.dst[g] = nullptr;
    p2.k0[g] = kL2[g][0]; p2.k1[g] = kL2[g][1];
    p2.thr[g] = 0x7fffffff; p2.addLo[g] = 0; p2.addHi[g] = 0;
    p2.rBase[g] = rB[g];
  }
  p1.rBase[3] = rB[3]; p2.rBase[3] = rB[3];
  p1.div = 1.0f; p2.div = 3.0f;
  unsigned gpropBlocks = (unsigned)(((size_t)rB[3] * 64 + 255) / 256);
  k_gprop3<<<gpropBlocks, 256, 0, stream>>>(p1);
  k_gprop3<<<gpropBlocks, 256, 0, stream>>>(p2);

  // ---------- aggregates (fused): SV_u from SV_v (uva), UV_s from UV_v (sva) ----------
  GA ga;
  ga.rp[0] = b.rp[3]; ga.cv[0] = b.cv[3];
  ga.src[0] = Ac[2] + (size_t)NSc * D;  // SV video part
  ga.dst[0] = SVuH; ga.k0[0] = kauv[0]; ga.k1[0] = kauv[1];
  ga.rp[1] = b.rp[4]; ga.cv[1] = b.cv[4];
  ga.src[1] = Ac[1] + (size_t)NUc * D;  // UV video part
  ga.dst[1] = UVsH; ga.k0[1] = kasv[0]; ga.k1[1] = kasv[1];
  ga.rBase[0] = 0; ga.rBase[1] = NUc; ga.rBase[2] = NUc + NSc;
  k_gagg2<<<(unsigned)(((size_t)(NUc + NSc) * 64 + 255) / 256), 256, 0, stream>>>(ga);

  // ---------- attention + losses ----------
  k_mga<<<(unsigned)((NUc + NSc + 3) / 4), 256, 0, stream>>>(Ac[0], Ac[1], UVsH, SVuH, Ac[2],
                                                             linW, linB);
  hipMemsetAsync(accs, 0, (size_t)(16 + 2 * Bc) * sizeof(float), stream);
  k_batch<<<(unsigned)((Bc + 3) / 4), 256, 0, stream>>>(Ac[0], users, streamers, Pu, Ps, accs);
  k_cgemm<<<dim3(Bc / 32, 4, 2), 256, 0, stream>>>(Pu, Ps, Su, Ss);
  k_cfinal<<<(unsigned)((2 * Bc + 3) / 4), 256, 0, stream>>>(Pu, Ps, Su, Ss, accs);
  k_final<<<1, 64, 0, stream>>>(accs, out);
}